// Round 5
// baseline (269.080 us; speedup 1.0000x reference)
//
#include <hip/hip_runtime.h>

typedef unsigned short u16;
typedef __attribute__((ext_vector_type(8))) short bf16x8;   // 8 bf16 in 4 VGPRs (MFMA A/B frag)
typedef __attribute__((ext_vector_type(4))) float f32x4;    // MFMA C/D frag

#define SS 2048
#define EE 1024
#define HH 16
#define DD 64

__device__ __forceinline__ float b2f(u16 u) {
  union { unsigned int i; float f; } v; v.i = ((unsigned int)u) << 16; return v.f;
}
__device__ __forceinline__ u16 f2b(float f) {
  union { float f; unsigned int i; } v; v.f = f;
  unsigned int i = v.i;
  return (u16)((i + 0x7FFFu + ((i >> 16) & 1u)) >> 16);  // RNE
}
__device__ __forceinline__ unsigned int cvt_pk_bf16(float lo, float hi) {
  unsigned int r;
  asm("v_cvt_pk_bf16_f32 %0, %1, %2" : "=v"(r) : "v"(lo), "v"(hi));  // RNE pack, low=lo
  return r;
}

// async global->LDS, 16B per lane (m97 pattern; LDS dest = wave-uniform base + lane*16)
#define GLD16(g, l)                                                         \
  __builtin_amdgcn_global_load_lds(                                         \
      (const __attribute__((address_space(1))) unsigned int*)(g),           \
      (__attribute__((address_space(3))) unsigned int*)(l), 16, 0, 0)

// ---------------- fused prep: qkv_w cvt | trig table | LayerNorm ----------------
// blocks [0,3072): cvt qkv_w -> bf16; [3072,3076): cos/sin table; [3076,7172): LN rows
__global__ __launch_bounds__(256) void k_prep(const float* __restrict__ qkv_w,
                                              u16* __restrict__ wq_b,
                                              const float* __restrict__ inv_freq,
                                              float2* __restrict__ cs,
                                              const float* __restrict__ x,
                                              const float* __restrict__ lw,
                                              const float* __restrict__ lb,
                                              u16* __restrict__ xn) {
  const int bx = blockIdx.x, t = threadIdx.x;
  if (bx < 3072) {
    const int i = bx * 256 + t;
    float4 v = ((const float4*)qkv_w)[i];
    ushort4 o;
    o.x = f2b(v.x); o.y = f2b(v.y); o.z = f2b(v.z); o.w = f2b(v.w);
    ((ushort4*)wq_b)[i] = o;
    return;
  }
  if (bx < 3076) {
    const int i = (bx - 3072) * 256 + t;
    float th = 2048.0f * inv_freq[i];
    cs[i] = make_float2(cosf(th), sinf(th));
    return;
  }
  const int row = bx - 3076;
  float4 v = ((const float4*)(x + (size_t)row * EE))[t];
  float f0 = v.x, f1 = v.y, f2 = v.z, f3 = v.w;
  float s = f0 + f1 + f2 + f3;
  float ss = f0 * f0 + f1 * f1 + f2 * f2 + f3 * f3;
  for (int o = 1; o < 64; o <<= 1) { s += __shfl_xor(s, o); ss += __shfl_xor(ss, o); }
  __shared__ float red[8];
  int w = t >> 6;
  if ((t & 63) == 0) { red[w] = s; red[4 + w] = ss; }
  __syncthreads();
  s = red[0] + red[1] + red[2] + red[3];
  ss = red[4] + red[5] + red[6] + red[7];
  float mu = s * (1.0f / 1024.0f);
  float var = ss * (1.0f / 1024.0f) - mu * mu;
  float rstd = rsqrtf(var + 1e-5f);
  float4 wv = ((const float4*)lw)[t];
  float4 bv = ((const float4*)lb)[t];
  ushort4 o;
  o.x = f2b((f0 - mu) * rstd * wv.x + bv.x);
  o.y = f2b((f1 - mu) * rstd * wv.y + bv.y);
  o.z = f2b((f2 - mu) * rstd * wv.z + bv.z);
  o.w = f2b((f3 - mu) * rstd * wv.w + bv.w);
  ((ushort4*)(xn + (size_t)row * EE))[t] = o;
}

// ---- MFMA GEMM  C[M,N] = A[M,K] * W[N,K]^T + bias (bf16 A and W) ----
// m97 structure: 128x128 tile, BK=32, linear LDS, global_load_lds x16
__global__ __launch_bounds__(256) void k_gemm_b(const u16* __restrict__ A,
                                                const u16* __restrict__ W,
                                                const float* __restrict__ bias,
                                                u16* __restrict__ C,
                                                int M, int N, int K) {
  __shared__ __align__(16) u16 As[128 * 32];
  __shared__ __align__(16) u16 Ws[128 * 32];
  const int t = threadIdx.x;
  const int m0 = blockIdx.y * 128, n0 = blockIdx.x * 128;
  const int lane = t & 63, w = t >> 6, quad = lane >> 4, l15 = lane & 15;
  const int wm = (w & 1) * 64, wn = (w >> 1) * 64;

  f32x4 zero4 = {0.f, 0.f, 0.f, 0.f};
  f32x4 acc[4][4];
  for (int mi = 0; mi < 4; mi++)
    for (int ni = 0; ni < 4; ni++) acc[mi][ni] = zero4;

  const u16* Ag = A + (size_t)(m0 + (t >> 2)) * K + (t & 3) * 8;
  const u16* Wg = W + (size_t)(n0 + (t >> 2)) * K + (t & 3) * 8;
  const size_t rowskip = (size_t)64 * K;

  for (int k0 = 0; k0 < K; k0 += 32) {
    GLD16(Ag + k0, As + t * 8);
    GLD16(Ag + rowskip + k0, As + 2048 + t * 8);
    GLD16(Wg + k0, Ws + t * 8);
    GLD16(Wg + rowskip + k0, Ws + 2048 + t * 8);
    __syncthreads();
    bf16x8 af[4], wf[4];
#pragma unroll
    for (int i = 0; i < 4; i++) {
      af[i] = *(const bf16x8*)(As + (wm + i * 16 + l15) * 32 + quad * 8);
      wf[i] = *(const bf16x8*)(Ws + (wn + i * 16 + l15) * 32 + quad * 8);
    }
#pragma unroll
    for (int mi = 0; mi < 4; mi++)
#pragma unroll
      for (int ni = 0; ni < 4; ni++)
        acc[mi][ni] = __builtin_amdgcn_mfma_f32_16x16x32_bf16(af[mi], wf[ni], acc[mi][ni], 0, 0, 0);
    __syncthreads();
  }
  for (int mi = 0; mi < 4; mi++)
    for (int ni = 0; ni < 4; ni++) {
      int col = n0 + wn + ni * 16 + l15;
      float bb = bias[col];
      for (int r = 0; r < 4; r++) {
        int grow = m0 + wm + mi * 16 + quad * 4 + r;
        C[(size_t)grow * N + col] = f2b(acc[mi][ni][r] + bb);
      }
    }
}

// ---- MFMA GEMM with fp32 W (converted in-flight; replaces k_cvt + bf16 gemm_f) ----
// 64x128 tile: As via GLD16; W fp32 reg-staged -> cvt_pk -> linear b128 ds_write
__global__ __launch_bounds__(256) void k_gemm_fw(const u16* __restrict__ A,
                                                 const float* __restrict__ W,
                                                 const float* __restrict__ bias,
                                                 float* __restrict__ C,
                                                 int M, int N, int K) {
  __shared__ __align__(16) u16 As[64 * 32];
  __shared__ __align__(16) u16 Ws[128 * 32];
  const int t = threadIdx.x;
  const int m0 = blockIdx.y * 64, n0 = blockIdx.x * 128;
  const int lane = t & 63, w = t >> 6, quad = lane >> 4, l15 = lane & 15;
  const int wm = (w & 1) * 32, wn = (w >> 1) * 64;

  f32x4 zero4 = {0.f, 0.f, 0.f, 0.f};
  f32x4 acc[2][4];
  for (int mi = 0; mi < 2; mi++)
    for (int ni = 0; ni < 4; ni++) acc[mi][ni] = zero4;

  const u16* Ag = A + (size_t)(m0 + (t >> 2)) * K + (t & 3) * 8;
  const float* Wg0 = W + (size_t)(n0 + (t >> 2)) * K + (t & 3) * 8;
  const float* Wg1 = Wg0 + (size_t)64 * K;

  for (int k0 = 0; k0 < K; k0 += 32) {
    GLD16(Ag + k0, As + t * 8);
    float4 wa = *(const float4*)(Wg0 + k0);
    float4 wb = *(const float4*)(Wg0 + k0 + 4);
    float4 wc = *(const float4*)(Wg1 + k0);
    float4 wd = *(const float4*)(Wg1 + k0 + 4);
    union { unsigned int u[4]; bf16x8 v8; } p0, p1;
    p0.u[0] = cvt_pk_bf16(wa.x, wa.y); p0.u[1] = cvt_pk_bf16(wa.z, wa.w);
    p0.u[2] = cvt_pk_bf16(wb.x, wb.y); p0.u[3] = cvt_pk_bf16(wb.z, wb.w);
    p1.u[0] = cvt_pk_bf16(wc.x, wc.y); p1.u[1] = cvt_pk_bf16(wc.z, wc.w);
    p1.u[2] = cvt_pk_bf16(wd.x, wd.y); p1.u[3] = cvt_pk_bf16(wd.z, wd.w);
    *(bf16x8*)(Ws + t * 8) = p0.v8;         // rows 0..63, linear (conflict-free)
    *(bf16x8*)(Ws + 2048 + t * 8) = p1.v8;  // rows 64..127
    __syncthreads();
    bf16x8 af[2], wf[4];
#pragma unroll
    for (int i = 0; i < 2; i++)
      af[i] = *(const bf16x8*)(As + (wm + i * 16 + l15) * 32 + quad * 8);
#pragma unroll
    for (int i = 0; i < 4; i++)
      wf[i] = *(const bf16x8*)(Ws + (wn + i * 16 + l15) * 32 + quad * 8);
#pragma unroll
    for (int mi = 0; mi < 2; mi++)
#pragma unroll
      for (int ni = 0; ni < 4; ni++)
        acc[mi][ni] = __builtin_amdgcn_mfma_f32_16x16x32_bf16(af[mi], wf[ni], acc[mi][ni], 0, 0, 0);
    __syncthreads();
  }
  for (int mi = 0; mi < 2; mi++)
    for (int ni = 0; ni < 4; ni++) {
      int col = n0 + wn + ni * 16 + l15;
      float bb = bias[col];
      for (int r = 0; r < 4; r++) {
        int grow = m0 + wm + mi * 16 + quad * 4 + r;
        C[(size_t)grow * N + col] = acc[mi][ni][r] + bb;
      }
    }
}

// ------ fused: rotate+l2norm+scale (all 4096 rows) | V transpose (blocks < 1024) ------
__global__ __launch_bounds__(256) void k_rotv(u16* __restrict__ qkv,
                                              const float2* __restrict__ cs_tab,
                                              const float* __restrict__ scale_p,
                                              u16* __restrict__ vt) {
  __shared__ float qf[1024];
  __shared__ float kf[1024];
  __shared__ __align__(16) u16 tile[64 * 72];
  const int row = blockIdx.x, t = threadIdx.x;
  {
    u16* qr = qkv + (size_t)row * 3072;
    u16* kr = qr + 1024;
    ushort4 qv = ((const ushort4*)qr)[t];
    ushort4 kv = ((const ushort4*)kr)[t];
    *(float4*)(qf + 4 * t) = make_float4(b2f(qv.x), b2f(qv.y), b2f(qv.z), b2f(qv.w));
    *(float4*)(kf + 4 * t) = make_float4(b2f(kv.x), b2f(kv.y), b2f(kv.z), b2f(kv.w));
    __syncthreads();
    const float scale = scale_p[0];
    float rq[4], rk[4];
#pragma unroll
    for (int u = 0; u < 4; u++) {
      int j = 4 * t + u;
      float2 cs = cs_tab[j];
      float qrot = (j < 512) ? -qf[2 * j + 1] : qf[2 * (j - 512)];
      float krot = (j < 512) ? -kf[2 * j + 1] : kf[2 * (j - 512)];
      rq[u] = qf[j] * cs.x + qrot * cs.y;
      rk[u] = kf[j] * cs.x + krot * cs.y;
    }
    float ssq = rq[0] * rq[0] + rq[1] * rq[1] + rq[2] * rq[2] + rq[3] * rq[3];
    float ssk = rk[0] * rk[0] + rk[1] * rk[1] + rk[2] * rk[2] + rk[3] * rk[3];
    for (int o = 1; o < 16; o <<= 1) { ssq += __shfl_xor(ssq, o); ssk += __shfl_xor(ssk, o); }
    float qs = scale / fmaxf(sqrtf(ssq), 1e-12f);
    float ks = scale / fmaxf(sqrtf(ssk), 1e-12f);
    ushort4 qo, ko;
    qo.x = f2b(rq[0] * qs); qo.y = f2b(rq[1] * qs); qo.z = f2b(rq[2] * qs); qo.w = f2b(rq[3] * qs);
    ko.x = f2b(rk[0] * ks); ko.y = f2b(rk[1] * ks); ko.z = f2b(rk[2] * ks); ko.w = f2b(rk[3] * ks);
    ((ushort4*)qr)[t] = qo;
    ((ushort4*)kr)[t] = ko;
  }
  if (row >= 1024) return;
  // ---- V transpose job (reads V section: untouched by the rotnorm phase) ----
  const int st = row & 31, bh = row >> 5;
  const int b = bh >> 4, h = bh & 15;
  const int s0 = st * 64;
  const int si = t >> 2, dc = t & 3;
  __syncthreads();  // LDS reuse safety (qf/kf reads done before tile writes)
  const u16* src = qkv + (size_t)(b * SS + s0 + si) * 3072 + 2048 + h * DD;
  bf16x8 v0 = *(const bf16x8*)(src + dc * 8);
  bf16x8 v1 = *(const bf16x8*)(src + (dc + 4) * 8);
#pragma unroll
  for (int u = 0; u < 8; u++) tile[(dc * 8 + u) * 72 + si] = (u16)v0[u];
#pragma unroll
  for (int u = 0; u < 8; u++) tile[((dc + 4) * 8 + u) * 72 + si] = (u16)v1[u];
  __syncthreads();
#pragma unroll
  for (int it = 0; it < 2; it++) {
    int idx = t + it * 256;
    int d = idx >> 3, ch = idx & 7;
    bf16x8 o = *(const bf16x8*)(tile + d * 72 + ch * 8);
    *(bf16x8*)(vt + (size_t)(bh * DD + d) * SS + s0 + ch * 8) = o;
  }
}

// ---------------- causal flash attention (MFMA) ----------------
// DUAL q-tile blocks: (qtA=bx, qtB=31-bx) processed CONCURRENTLY in one kt loop.
// Shared K/V staging for kt<=limA (staging iters 17 -> limB+1, avg 12.5);
// two independent QK->softmax->PV chains per iter (PtA/PtB) for ILP.
// KBLK=128, sigma-permuted P/V columns (k=n*16+m -> m*8+n on both Pt and Vt).
__global__ __launch_bounds__(256) void k_attn(const u16* __restrict__ qkv,
                                              const u16* __restrict__ vt,
                                              u16* __restrict__ out) {
  __shared__ __align__(16) u16 Kt[128 * 72];
  __shared__ __align__(16) u16 Vt[64 * 136];
  __shared__ __align__(16) u16 PtA[64 * 136];
  __shared__ __align__(16) u16 PtB[64 * 136];
  const int bh = blockIdx.y;
  const int b = bh >> 4, h = bh & 15;
  const int t = threadIdx.x, w = t >> 6, lane = t & 63, quad = lane >> 4, l15 = lane & 15;
  const int kr = t >> 1, kdh = (t & 1) * 32;  // K staging: row (0..127), d-half
  const int dr = t >> 2, kc4 = t & 3;         // V staging: d-row (0..63), k-quarter
  const u16* kn = qkv + 1024;
  f32x4 zero4 = {0.f, 0.f, 0.f, 0.f};

  const int qtA = blockIdx.x;        // 0..15
  const int qtB = 31 - qtA;          // 16..31
  const int limA = qtA >> 1;         // diag 128-tile for A
  const int limB = qtB >> 1;         // diag 128-tile for B (= loop bound)
  const int q0A = qtA * 64, q0B = qtB * 64;

  bf16x8 qfA[2], qfB[2];
  {
    const u16* qa = qkv + (size_t)(b * SS + q0A + 16 * w + l15) * 3072 + h * DD;
    qfA[0] = *(const bf16x8*)(qa + quad * 8);
    qfA[1] = *(const bf16x8*)(qa + 32 + quad * 8);
    const u16* qb = qkv + (size_t)(b * SS + q0B + 16 * w + l15) * 3072 + h * DD;
    qfB[0] = *(const bf16x8*)(qb + quad * 8);
    qfB[1] = *(const bf16x8*)(qb + 32 + quad * 8);
  }
  f32x4 oA[4], oB[4];
  for (int n = 0; n < 4; n++) { oA[n] = zero4; oB[n] = zero4; }
  float mA[4] = {-1e30f, -1e30f, -1e30f, -1e30f}, lA[4] = {0.f, 0.f, 0.f, 0.f};
  float mB[4] = {-1e30f, -1e30f, -1e30f, -1e30f}, lB[4] = {0.f, 0.f, 0.f, 0.f};

  bf16x8 kv[4], vv[4];
  // prologue: load & stage tile kt=0
  {
    const u16* krow = kn + (size_t)(b * SS + kr) * 3072 + h * DD + kdh;
    const u16* vrow = vt + (size_t)(bh * DD + dr) * SS + kc4 * 32;
#pragma unroll
    for (int j = 0; j < 4; j++) kv[j] = *(const bf16x8*)(krow + j * 8);
#pragma unroll
    for (int j = 0; j < 4; j++) vv[j] = *(const bf16x8*)(vrow + j * 8);
  }
#pragma unroll
  for (int j = 0; j < 4; j++) *(bf16x8*)(Kt + kr * 72 + kdh + j * 8) = kv[j];
#pragma unroll
  for (int j = 0; j < 4; j++) {
    const int ch = kc4 * 4 + j;
    u16* vb = Vt + dr * 136 + (ch & 1) * 64 + (ch >> 1);
#pragma unroll
    for (int e = 0; e < 8; e++) vb[e * 8] = (u16)vv[j][e];
  }
  __syncthreads();

  for (int kt = 0; kt <= limB; kt++) {
    if (kt < limB) {  // prefetch next tile into regs; staged after bottom barrier
      const int k0n = (kt + 1) * 128;
      const u16* krow = kn + (size_t)(b * SS + k0n + kr) * 3072 + h * DD + kdh;
      const u16* vrow = vt + (size_t)(bh * DD + dr) * SS + k0n + kc4 * 32;
#pragma unroll
      for (int j = 0; j < 4; j++) kv[j] = *(const bf16x8*)(krow + j * 8);
#pragma unroll
      for (int j = 0; j < 4; j++) vv[j] = *(const bf16x8*)(vrow + j * 8);
    }
    // ---- QK^T for B (always) ----
    f32x4 sB[8];
#pragma unroll
    for (int n = 0; n < 8; n++) {
      sB[n] = zero4;
#pragma unroll
      for (int c = 0; c < 2; c++) {
        bf16x8 kfrag = *(const bf16x8*)(Kt + (n * 16 + l15) * 72 + c * 32 + quad * 8);
        sB[n] = __builtin_amdgcn_mfma_f32_16x16x32_bf16(qfB[c], kfrag, sB[n], 0, 0, 0);
      }
    }
    if (kt == limB) {
      const int rb = (qtB & 1) * 64 + 16 * w + quad * 4;
#pragma unroll
      for (int n = 0; n < 8; n++)
#pragma unroll
        for (int r = 0; r < 4; r++)
          if (n * 16 + l15 > rb + r) sB[n][r] = -1e30f;
    }
    if (kt <= limA) {
      // ---- both tiles active: interleaved independent chains ----
      f32x4 sA[8];
#pragma unroll
      for (int n = 0; n < 8; n++) {
        sA[n] = zero4;
#pragma unroll
        for (int c = 0; c < 2; c++) {
          bf16x8 kfrag = *(const bf16x8*)(Kt + (n * 16 + l15) * 72 + c * 32 + quad * 8);
          sA[n] = __builtin_amdgcn_mfma_f32_16x16x32_bf16(qfA[c], kfrag, sA[n], 0, 0, 0);
        }
      }
      if (kt == limA) {
        const int ra = (qtA & 1) * 64 + 16 * w + quad * 4;
#pragma unroll
        for (int n = 0; n < 8; n++)
#pragma unroll
          for (int r = 0; r < 4; r++)
            if (n * 16 + l15 > ra + r) sA[n][r] = -1e30f;
      }
#pragma unroll
      for (int r = 0; r < 4; r++) {
        float mxB = fmaxf(fmaxf(fmaxf(sB[0][r], sB[1][r]), fmaxf(sB[2][r], sB[3][r])),
                          fmaxf(fmaxf(sB[4][r], sB[5][r]), fmaxf(sB[6][r], sB[7][r])));
        float mxA = fmaxf(fmaxf(fmaxf(sA[0][r], sA[1][r]), fmaxf(sA[2][r], sA[3][r])),
                          fmaxf(fmaxf(sA[4][r], sA[5][r]), fmaxf(sA[6][r], sA[7][r])));
        for (int o = 1; o < 16; o <<= 1) {
          mxB = fmaxf(mxB, __shfl_xor(mxB, o));
          mxA = fmaxf(mxA, __shfl_xor(mxA, o));
        }
        float mnB = fmaxf(mB[r], mxB), mnA = fmaxf(mA[r], mxA);
        float alB = __expf(mB[r] - mnB), alA = __expf(mA[r] - mnA);
        mB[r] = mnB; mA[r] = mnA;
        float rsB = 0.f, rsA = 0.f;
#pragma unroll
        for (int n = 0; n < 8; n++) {
          float pB = __expf(sB[n][r] - mnB); sB[n][r] = pB; rsB += pB;
          float pA = __expf(sA[n][r] - mnA); sA[n][r] = pA; rsA += pA;
        }
        for (int o = 1; o < 16; o <<= 1) {
          rsB += __shfl_xor(rsB, o);
          rsA += __shfl_xor(rsA, o);
        }
        lB[r] = alB * lB[r] + rsB;
        lA[r] = alA * lA[r] + rsA;
#pragma unroll
        for (int n = 0; n < 4; n++) { oB[n][r] *= alB; oA[n][r] *= alA; }
      }
#pragma unroll
      for (int r = 0; r < 4; r++) {
        union { unsigned int u[4]; bf16x8 v8; } pb, pa;
        pb.u[0] = cvt_pk_bf16(sB[0][r], sB[1][r]); pb.u[1] = cvt_pk_bf16(sB[2][r], sB[3][r]);
        pb.u[2] = cvt_pk_bf16(sB[4][r], sB[5][r]); pb.u[3] = cvt_pk_bf16(sB[6][r], sB[7][r]);
        pa.u[0] = cvt_pk_bf16(sA[0][r], sA[1][r]); pa.u[1] = cvt_pk_bf16(sA[2][r], sA[3][r]);
        pa.u[2] = cvt_pk_bf16(sA[4][r], sA[5][r]); pa.u[3] = cvt_pk_bf16(sA[6][r], sA[7][r]);
        *(bf16x8*)(PtB + (16 * w + quad * 4 + r) * 136 + l15 * 8) = pb.v8;
        *(bf16x8*)(PtA + (16 * w + quad * 4 + r) * 136 + l15 * 8) = pa.v8;
      }
      asm volatile("s_waitcnt lgkmcnt(0)" ::: "memory");
      __builtin_amdgcn_sched_barrier(0);
#pragma unroll
      for (int c = 0; c < 4; c++) {
        bf16x8 pfB = *(const bf16x8*)(PtB + (16 * w + l15) * 136 + c * 32 + quad * 8);
        bf16x8 pfA = *(const bf16x8*)(PtA + (16 * w + l15) * 136 + c * 32 + quad * 8);
#pragma unroll
        for (int n = 0; n < 4; n++) {
          bf16x8 vf = *(const bf16x8*)(Vt + (n * 16 + l15) * 136 + c * 32 + quad * 8);
          oB[n] = __builtin_amdgcn_mfma_f32_16x16x32_bf16(pfB, vf, oB[n], 0, 0, 0);
          oA[n] = __builtin_amdgcn_mfma_f32_16x16x32_bf16(pfA, vf, oA[n], 0, 0, 0);
        }
      }
    } else {
      // ---- B only (tail region) ----
#pragma unroll
      for (int r = 0; r < 4; r++) {
        float mx = fmaxf(fmaxf(fmaxf(sB[0][r], sB[1][r]), fmaxf(sB[2][r], sB[3][r])),
                         fmaxf(fmaxf(sB[4][r], sB[5][r]), fmaxf(sB[6][r], sB[7][r])));
        for (int o = 1; o < 16; o <<= 1) mx = fmaxf(mx, __shfl_xor(mx, o));
        float mn = fmaxf(mB[r], mx);
        float al = __expf(mB[r] - mn);
        mB[r] = mn;
        float rs = 0.f;
#pragma unroll
        for (int n = 0; n < 8; n++) {
          float p = __expf(sB[n][r] - mn);
          sB[n][r] = p;
          rs += p;
        }
        for (int o = 1; o < 16; o <<= 1) rs += __shfl_xor(rs, o);
        lB[r] = al * lB[r] + rs;
#pragma unroll
        for (int n = 0; n < 4; n++) oB[n][r] *= al;
      }
#pragma unroll
      for (int r = 0; r < 4; r++) {
        union { unsigned int u[4]; bf16x8 v8; } pb;
        pb.u[0] = cvt_pk_bf16(sB[0][r], sB[1][r]); pb.u[1] = cvt_pk_bf16(sB[2][r], sB[3][r]);
        pb.u[2] = cvt_pk_bf16(sB[4][r], sB[5][r]); pb.u[3] = cvt_pk_bf16(sB[6][r], sB[7][r]);
        *(bf16x8*)(PtB + (16 * w + quad * 4 + r) * 136 + l15 * 8) = pb.v8;
      }
      asm volatile("s_waitcnt lgkmcnt(0)" ::: "memory");
      __builtin_amdgcn_sched_barrier(0);
#pragma unroll
      for (int c = 0; c < 4; c++) {
        bf16x8 pf = *(const bf16x8*)(PtB + (16 * w + l15) * 136 + c * 32 + quad * 8);
#pragma unroll
        for (int n = 0; n < 4; n++) {
          bf16x8 vf = *(const bf16x8*)(Vt + (n * 16 + l15) * 136 + c * 32 + quad * 8);
          oB[n] = __builtin_amdgcn_mfma_f32_16x16x32_bf16(pf, vf, oB[n], 0, 0, 0);
        }
      }
    }
    __syncthreads();  // all warps done reading Kt/Vt of tile kt
    if (kt < limB) {  // stage prefetched tile kt+1
#pragma unroll
      for (int j = 0; j < 4; j++) *(bf16x8*)(Kt + kr * 72 + kdh + j * 8) = kv[j];
#pragma unroll
      for (int j = 0; j < 4; j++) {
        const int ch = kc4 * 4 + j;
        u16* vb = Vt + dr * 136 + (ch & 1) * 64 + (ch >> 1);
#pragma unroll
        for (int e = 0; e < 8; e++) vb[e * 8] = (u16)vv[j][e];
      }
    }
    __syncthreads();  // staged tile visible
  }
  for (int n = 0; n < 4; n++)
    for (int r = 0; r < 4; r++) {
      int rowA = q0A + 16 * w + quad * 4 + r;
      int rowB = q0B + 16 * w + quad * 4 + r;
      out[(size_t)(b * SS + rowA) * EE + h * DD + n * 16 + l15] = f2b(oA[n][r] / lA[r]);
      out[(size_t)(b * SS + rowB) * EE + h * DD + n * 16 + l15] = f2b(oB[n][r] / lB[r]);
    }
}

extern "C" void kernel_launch(void* const* d_in, const int* in_sizes, int n_in,
                              void* d_out, int out_size, void* d_ws, size_t ws_size,
                              hipStream_t stream) {
  const float* x       = (const float*)d_in[0];
  const float* ln_w    = (const float*)d_in[1];
  const float* ln_b    = (const float*)d_in[2];
  const float* qkv_w   = (const float*)d_in[3];
  const float* qkv_b   = (const float*)d_in[4];
  const float* qk_s    = (const float*)d_in[5];
  const float* out_w   = (const float*)d_in[6];
  const float* out_b   = (const float*)d_in[7];
  const float* inv_frq = (const float*)d_in[8];

  // ws (33.55 MB): xn bf16 [8.39 MB] | qkv bf16 [25.17 MB]
  u16* ws   = (u16*)d_ws;
  u16* xn   = ws;                               // 4096*1024 (LN out, later attn out)
  u16* qkv  = ws + (size_t)4096 * 1024;         // 4096*3072 (q,k normalized in place)
  // d_out is fp32 [16.78 MB]; stage bf16 scratch inside it while it's dead:
  u16* wq_b = (u16*)d_out;                      // [0, 6.29 MB): bf16 qkv_w
  float2* cs_tab = (float2*)((char*)d_out + 6291456);  // [6.29, 6.30 MB): cos/sin table
  u16* vt   = (u16*)d_out + (size_t)4194304;    // [8.39, 16.78 MB): bf16 V^T

  k_prep<<<7172, 256, 0, stream>>>(qkv_w, wq_b, inv_frq, cs_tab, x, ln_w, ln_b, xn);
  k_gemm_b<<<dim3(24, 32), 256, 0, stream>>>(xn, wq_b, qkv_b, qkv, 4096, 3072, 1024);
  k_rotv<<<4096, 256, 0, stream>>>(qkv, cs_tab, qk_s, vt);
  k_attn<<<dim3(16, 32), 256, 0, stream>>>(qkv, vt, xn);
  k_gemm_fw<<<dim3(8, 64), 256, 0, stream>>>(xn, out_w, out_b, (float*)d_out, 4096, 1024, 1024);
}

// Round 7
// 231.461 us; speedup vs baseline: 1.1625x; 1.1625x over previous
//
#include <hip/hip_runtime.h>

typedef unsigned short u16;
typedef __attribute__((ext_vector_type(8))) short bf16x8;   // 8 bf16 in 4 VGPRs (MFMA A/B frag)
typedef __attribute__((ext_vector_type(4))) float f32x4;    // MFMA C/D frag

#define SS 2048
#define EE 1024
#define HH 16
#define DD 64

__device__ __forceinline__ float b2f(u16 u) {
  union { unsigned int i; float f; } v; v.i = ((unsigned int)u) << 16; return v.f;
}
__device__ __forceinline__ u16 f2b(float f) {
  union { float f; unsigned int i; } v; v.f = f;
  unsigned int i = v.i;
  return (u16)((i + 0x7FFFu + ((i >> 16) & 1u)) >> 16);  // RNE
}
__device__ __forceinline__ unsigned int cvt_pk_bf16(float lo, float hi) {
  unsigned int r;
  asm("v_cvt_pk_bf16_f32 %0, %1, %2" : "=v"(r) : "v"(lo), "v"(hi));  // RNE pack, low=lo
  return r;
}

// async global->LDS, 16B per lane (m97 pattern; LDS dest = wave-uniform base + lane*16)
#define GLD16(g, l)                                                         \
  __builtin_amdgcn_global_load_lds(                                         \
      (const __attribute__((address_space(1))) unsigned int*)(g),           \
      (__attribute__((address_space(3))) unsigned int*)(l), 16, 0, 0)

// ---------------- fused prep: qkv_w cvt | trig table | LayerNorm ----------------
// blocks [0,3072): cvt qkv_w -> bf16; [3072,3076): cos/sin table; [3076,7172): LN rows
__global__ __launch_bounds__(256) void k_prep(const float* __restrict__ qkv_w,
                                              u16* __restrict__ wq_b,
                                              const float* __restrict__ inv_freq,
                                              float2* __restrict__ cs,
                                              const float* __restrict__ x,
                                              const float* __restrict__ lw,
                                              const float* __restrict__ lb,
                                              u16* __restrict__ xn) {
  const int bx = blockIdx.x, t = threadIdx.x;
  if (bx < 3072) {
    const int i = bx * 256 + t;
    float4 v = ((const float4*)qkv_w)[i];
    ushort4 o;
    o.x = f2b(v.x); o.y = f2b(v.y); o.z = f2b(v.z); o.w = f2b(v.w);
    ((ushort4*)wq_b)[i] = o;
    return;
  }
  if (bx < 3076) {
    const int i = (bx - 3072) * 256 + t;
    float th = 2048.0f * inv_freq[i];
    cs[i] = make_float2(cosf(th), sinf(th));
    return;
  }
  const int row = bx - 3076;
  float4 v = ((const float4*)(x + (size_t)row * EE))[t];
  float f0 = v.x, f1 = v.y, f2 = v.z, f3 = v.w;
  float s = f0 + f1 + f2 + f3;
  float ss = f0 * f0 + f1 * f1 + f2 * f2 + f3 * f3;
  for (int o = 1; o < 64; o <<= 1) { s += __shfl_xor(s, o); ss += __shfl_xor(ss, o); }
  __shared__ float red[8];
  int w = t >> 6;
  if ((t & 63) == 0) { red[w] = s; red[4 + w] = ss; }
  __syncthreads();
  s = red[0] + red[1] + red[2] + red[3];
  ss = red[4] + red[5] + red[6] + red[7];
  float mu = s * (1.0f / 1024.0f);
  float var = ss * (1.0f / 1024.0f) - mu * mu;
  float rstd = rsqrtf(var + 1e-5f);
  float4 wv = ((const float4*)lw)[t];
  float4 bv = ((const float4*)lb)[t];
  ushort4 o;
  o.x = f2b((f0 - mu) * rstd * wv.x + bv.x);
  o.y = f2b((f1 - mu) * rstd * wv.y + bv.y);
  o.z = f2b((f2 - mu) * rstd * wv.z + bv.z);
  o.w = f2b((f3 - mu) * rstd * wv.w + bv.w);
  ((ushort4*)(xn + (size_t)row * EE))[t] = o;
}

// ---- MFMA GEMM  C[M,N] = A[M,K] * W[N,K]^T + bias (bf16 A and W) ----
// m97 structure: 128x128 tile, BK=32, linear LDS, global_load_lds x16
__global__ __launch_bounds__(256) void k_gemm_b(const u16* __restrict__ A,
                                                const u16* __restrict__ W,
                                                const float* __restrict__ bias,
                                                u16* __restrict__ C,
                                                int M, int N, int K) {
  __shared__ __align__(16) u16 As[128 * 32];
  __shared__ __align__(16) u16 Ws[128 * 32];
  const int t = threadIdx.x;
  const int m0 = blockIdx.y * 128, n0 = blockIdx.x * 128;
  const int lane = t & 63, w = t >> 6, quad = lane >> 4, l15 = lane & 15;
  const int wm = (w & 1) * 64, wn = (w >> 1) * 64;

  f32x4 zero4 = {0.f, 0.f, 0.f, 0.f};
  f32x4 acc[4][4];
  for (int mi = 0; mi < 4; mi++)
    for (int ni = 0; ni < 4; ni++) acc[mi][ni] = zero4;

  const u16* Ag = A + (size_t)(m0 + (t >> 2)) * K + (t & 3) * 8;
  const u16* Wg = W + (size_t)(n0 + (t >> 2)) * K + (t & 3) * 8;
  const size_t rowskip = (size_t)64 * K;

  for (int k0 = 0; k0 < K; k0 += 32) {
    GLD16(Ag + k0, As + t * 8);
    GLD16(Ag + rowskip + k0, As + 2048 + t * 8);
    GLD16(Wg + k0, Ws + t * 8);
    GLD16(Wg + rowskip + k0, Ws + 2048 + t * 8);
    __syncthreads();
    bf16x8 af[4], wf[4];
#pragma unroll
    for (int i = 0; i < 4; i++) {
      af[i] = *(const bf16x8*)(As + (wm + i * 16 + l15) * 32 + quad * 8);
      wf[i] = *(const bf16x8*)(Ws + (wn + i * 16 + l15) * 32 + quad * 8);
    }
#pragma unroll
    for (int mi = 0; mi < 4; mi++)
#pragma unroll
      for (int ni = 0; ni < 4; ni++)
        acc[mi][ni] = __builtin_amdgcn_mfma_f32_16x16x32_bf16(af[mi], wf[ni], acc[mi][ni], 0, 0, 0);
    __syncthreads();
  }
  for (int mi = 0; mi < 4; mi++)
    for (int ni = 0; ni < 4; ni++) {
      int col = n0 + wn + ni * 16 + l15;
      float bb = bias[col];
      for (int r = 0; r < 4; r++) {
        int grow = m0 + wm + mi * 16 + quad * 4 + r;
        C[(size_t)grow * N + col] = f2b(acc[mi][ni][r] + bb);
      }
    }
}

// ---- MFMA GEMM with fp32 W (converted in-flight; replaces k_cvt + bf16 gemm_f) ----
// 64x128 tile: As via GLD16; W fp32 reg-staged -> cvt_pk -> linear b128 ds_write
__global__ __launch_bounds__(256) void k_gemm_fw(const u16* __restrict__ A,
                                                 const float* __restrict__ W,
                                                 const float* __restrict__ bias,
                                                 float* __restrict__ C,
                                                 int M, int N, int K) {
  __shared__ __align__(16) u16 As[64 * 32];
  __shared__ __align__(16) u16 Ws[128 * 32];
  const int t = threadIdx.x;
  const int m0 = blockIdx.y * 64, n0 = blockIdx.x * 128;
  const int lane = t & 63, w = t >> 6, quad = lane >> 4, l15 = lane & 15;
  const int wm = (w & 1) * 32, wn = (w >> 1) * 64;

  f32x4 zero4 = {0.f, 0.f, 0.f, 0.f};
  f32x4 acc[2][4];
  for (int mi = 0; mi < 2; mi++)
    for (int ni = 0; ni < 4; ni++) acc[mi][ni] = zero4;

  const u16* Ag = A + (size_t)(m0 + (t >> 2)) * K + (t & 3) * 8;
  const float* Wg0 = W + (size_t)(n0 + (t >> 2)) * K + (t & 3) * 8;
  const float* Wg1 = Wg0 + (size_t)64 * K;

  for (int k0 = 0; k0 < K; k0 += 32) {
    GLD16(Ag + k0, As + t * 8);
    float4 wa = *(const float4*)(Wg0 + k0);
    float4 wb = *(const float4*)(Wg0 + k0 + 4);
    float4 wc = *(const float4*)(Wg1 + k0);
    float4 wd = *(const float4*)(Wg1 + k0 + 4);
    union { unsigned int u[4]; bf16x8 v8; } p0, p1;
    p0.u[0] = cvt_pk_bf16(wa.x, wa.y); p0.u[1] = cvt_pk_bf16(wa.z, wa.w);
    p0.u[2] = cvt_pk_bf16(wb.x, wb.y); p0.u[3] = cvt_pk_bf16(wb.z, wb.w);
    p1.u[0] = cvt_pk_bf16(wc.x, wc.y); p1.u[1] = cvt_pk_bf16(wc.z, wc.w);
    p1.u[2] = cvt_pk_bf16(wd.x, wd.y); p1.u[3] = cvt_pk_bf16(wd.z, wd.w);
    *(bf16x8*)(Ws + t * 8) = p0.v8;         // rows 0..63, linear (conflict-free)
    *(bf16x8*)(Ws + 2048 + t * 8) = p1.v8;  // rows 64..127
    __syncthreads();
    bf16x8 af[2], wf[4];
#pragma unroll
    for (int i = 0; i < 2; i++)
      af[i] = *(const bf16x8*)(As + (wm + i * 16 + l15) * 32 + quad * 8);
#pragma unroll
    for (int i = 0; i < 4; i++)
      wf[i] = *(const bf16x8*)(Ws + (wn + i * 16 + l15) * 32 + quad * 8);
#pragma unroll
    for (int mi = 0; mi < 2; mi++)
#pragma unroll
      for (int ni = 0; ni < 4; ni++)
        acc[mi][ni] = __builtin_amdgcn_mfma_f32_16x16x32_bf16(af[mi], wf[ni], acc[mi][ni], 0, 0, 0);
    __syncthreads();
  }
  for (int mi = 0; mi < 2; mi++)
    for (int ni = 0; ni < 4; ni++) {
      int col = n0 + wn + ni * 16 + l15;
      float bb = bias[col];
      for (int r = 0; r < 4; r++) {
        int grow = m0 + wm + mi * 16 + quad * 4 + r;
        C[(size_t)grow * N + col] = acc[mi][ni][r] + bb;
      }
    }
}

// ------ fused: rotate+l2norm+scale (all 4096 rows) | V transpose (blocks < 1024) ------
__global__ __launch_bounds__(256) void k_rotv(u16* __restrict__ qkv,
                                              const float2* __restrict__ cs_tab,
                                              const float* __restrict__ scale_p,
                                              u16* __restrict__ vt) {
  __shared__ float qf[1024];
  __shared__ float kf[1024];
  __shared__ __align__(16) u16 tile[64 * 72];
  const int row = blockIdx.x, t = threadIdx.x;
  {
    u16* qr = qkv + (size_t)row * 3072;
    u16* kr = qr + 1024;
    ushort4 qv = ((const ushort4*)qr)[t];
    ushort4 kv = ((const ushort4*)kr)[t];
    *(float4*)(qf + 4 * t) = make_float4(b2f(qv.x), b2f(qv.y), b2f(qv.z), b2f(qv.w));
    *(float4*)(kf + 4 * t) = make_float4(b2f(kv.x), b2f(kv.y), b2f(kv.z), b2f(kv.w));
    __syncthreads();
    const float scale = scale_p[0];
    float rq[4], rk[4];
#pragma unroll
    for (int u = 0; u < 4; u++) {
      int j = 4 * t + u;
      float2 cs = cs_tab[j];
      float qrot = (j < 512) ? -qf[2 * j + 1] : qf[2 * (j - 512)];
      float krot = (j < 512) ? -kf[2 * j + 1] : kf[2 * (j - 512)];
      rq[u] = qf[j] * cs.x + qrot * cs.y;
      rk[u] = kf[j] * cs.x + krot * cs.y;
    }
    float ssq = rq[0] * rq[0] + rq[1] * rq[1] + rq[2] * rq[2] + rq[3] * rq[3];
    float ssk = rk[0] * rk[0] + rk[1] * rk[1] + rk[2] * rk[2] + rk[3] * rk[3];
    for (int o = 1; o < 16; o <<= 1) { ssq += __shfl_xor(ssq, o); ssk += __shfl_xor(ssk, o); }
    float qs = scale / fmaxf(sqrtf(ssq), 1e-12f);
    float ks = scale / fmaxf(sqrtf(ssk), 1e-12f);
    ushort4 qo, ko;
    qo.x = f2b(rq[0] * qs); qo.y = f2b(rq[1] * qs); qo.z = f2b(rq[2] * qs); qo.w = f2b(rq[3] * qs);
    ko.x = f2b(rk[0] * ks); ko.y = f2b(rk[1] * ks); ko.z = f2b(rk[2] * ks); ko.w = f2b(rk[3] * ks);
    ((ushort4*)qr)[t] = qo;
    ((ushort4*)kr)[t] = ko;
  }
  if (row >= 1024) return;
  // ---- V transpose job (reads V section: untouched by the rotnorm phase) ----
  const int st = row & 31, bh = row >> 5;
  const int b = bh >> 4, h = bh & 15;
  const int s0 = st * 64;
  const int si = t >> 2, dc = t & 3;
  __syncthreads();  // LDS reuse safety (qf/kf reads done before tile writes)
  const u16* src = qkv + (size_t)(b * SS + s0 + si) * 3072 + 2048 + h * DD;
  bf16x8 v0 = *(const bf16x8*)(src + dc * 8);
  bf16x8 v1 = *(const bf16x8*)(src + (dc + 4) * 8);
#pragma unroll
  for (int u = 0; u < 8; u++) tile[(dc * 8 + u) * 72 + si] = (u16)v0[u];
#pragma unroll
  for (int u = 0; u < 8; u++) tile[((dc + 4) * 8 + u) * 72 + si] = (u16)v1[u];
  __syncthreads();
#pragma unroll
  for (int it = 0; it < 2; it++) {
    int idx = t + it * 256;
    int d = idx >> 3, ch = idx & 7;
    bf16x8 o = *(const bf16x8*)(tile + d * 72 + ch * 8);
    *(bf16x8*)(vt + (size_t)(bh * DD + d) * SS + s0 + ch * 8) = o;
  }
}

// ---------------- causal flash attention (MFMA) ----------------
// QBLK=128 via 8 warps (512 thr): warp w owns q-rows 16w..16w+15 — per-warp code
// identical to the proven round-4 kernel (same ~116 VGPR), but each staged K/V
// tile feeds 128 q-rows: staging/barriers/HBM per unit MFMA work are HALVED.
// KBLK=128; paired q-tiles (qt128=bx, 15-bx): uniform 17 iterations per block.
// sigma-permuted P/V columns (k=n*16+m -> m*8+n on BOTH Pt and Vt; MFMA contraction
// is invariant to a consistent k-permutation).
// Retry note: identical to the round-6 submission except the Pt write->read sync
// is a plain __syncthreads (conservative; lgkmcnt-only was unvalidated at 8 waves).
__global__ __launch_bounds__(512) void k_attn(const u16* __restrict__ qkv,
                                              const u16* __restrict__ vt,
                                              u16* __restrict__ out) {
  __shared__ __align__(16) u16 Kt[128 * 72];
  __shared__ __align__(16) u16 Vt[64 * 136];
  __shared__ __align__(16) u16 Pt[128 * 136];
  const int bh = blockIdx.y;
  const int b = bh >> 4, h = bh & 15;
  const int t = threadIdx.x, w = t >> 6, lane = t & 63, quad = lane >> 4, l15 = lane & 15;
  const int krow = t >> 2, kq = (t & 3) * 16;  // K staging: row 0..127, 16-u16 quarter
  const int dr = t >> 3, kc8 = t & 7;          // V staging: d-row 0..63, 16-k eighth
  const u16* kn = qkv + 1024;
  f32x4 zero4 = {0.f, 0.f, 0.f, 0.f};

  for (int rep = 0; rep < 2; rep++) {
    const int qt = rep ? 15 - (int)blockIdx.x : (int)blockIdx.x;  // 128-row q-tile
    const int q0 = qt * 128;

    bf16x8 qf[2];
    {
      const u16* qrow = qkv + (size_t)(b * SS + q0 + 16 * w + l15) * 3072 + h * DD;
      qf[0] = *(const bf16x8*)(qrow + quad * 8);
      qf[1] = *(const bf16x8*)(qrow + 32 + quad * 8);
    }
    f32x4 oacc[4];
    for (int n = 0; n < 4; n++) oacc[n] = zero4;
    float m_i[4] = {-1e30f, -1e30f, -1e30f, -1e30f};
    float l_i[4] = {0.f, 0.f, 0.f, 0.f};

    bf16x8 kv[2], vv[2];
    // prologue: load & stage tile kt=0
    {
      const u16* krg = kn + (size_t)(b * SS + krow) * 3072 + h * DD + kq;
      kv[0] = *(const bf16x8*)(krg);
      kv[1] = *(const bf16x8*)(krg + 8);
      const u16* vrg = vt + (size_t)(bh * DD + dr) * SS + kc8 * 16;
      vv[0] = *(const bf16x8*)(vrg);
      vv[1] = *(const bf16x8*)(vrg + 8);
    }
    __syncthreads();  // previous rep's readers done before overwriting buffers
    *(bf16x8*)(Kt + krow * 72 + kq) = kv[0];
    *(bf16x8*)(Kt + krow * 72 + kq + 8) = kv[1];
#pragma unroll
    for (int j = 0; j < 2; j++) {
      const int ch = kc8 * 2 + j;
      u16* vb = Vt + dr * 136 + (ch & 1) * 64 + (ch >> 1);
#pragma unroll
      for (int e = 0; e < 8; e++) vb[e * 8] = (u16)vv[j][e];
    }
    __syncthreads();

    for (int kt = 0; kt <= qt; kt++) {
      if (kt < qt) {  // prefetch next tile into regs; staged after bottom barrier
        const int k0n = (kt + 1) * 128;
        const u16* krg = kn + (size_t)(b * SS + k0n + krow) * 3072 + h * DD + kq;
        kv[0] = *(const bf16x8*)(krg);
        kv[1] = *(const bf16x8*)(krg + 8);
        const u16* vrg = vt + (size_t)(bh * DD + dr) * SS + k0n + kc8 * 16;
        vv[0] = *(const bf16x8*)(vrg);
        vv[1] = *(const bf16x8*)(vrg + 8);
      }
      f32x4 sacc[8];
#pragma unroll
      for (int n = 0; n < 8; n++) {
        sacc[n] = zero4;
#pragma unroll
        for (int c = 0; c < 2; c++) {
          bf16x8 kfrag = *(const bf16x8*)(Kt + (n * 16 + l15) * 72 + c * 32 + quad * 8);
          sacc[n] = __builtin_amdgcn_mfma_f32_16x16x32_bf16(qf[c], kfrag, sacc[n], 0, 0, 0);
        }
      }
      if (kt == qt) {  // diagonal tile: mask col > row-in-tile (QBLK == KBLK == 128)
        const int rbase = 16 * w + quad * 4;
#pragma unroll
        for (int n = 0; n < 8; n++)
#pragma unroll
          for (int r = 0; r < 4; r++)
            if (n * 16 + l15 > rbase + r) sacc[n][r] = -1e30f;
      }
#pragma unroll
      for (int r = 0; r < 4; r++) {
        float mx = fmaxf(fmaxf(fmaxf(sacc[0][r], sacc[1][r]), fmaxf(sacc[2][r], sacc[3][r])),
                         fmaxf(fmaxf(sacc[4][r], sacc[5][r]), fmaxf(sacc[6][r], sacc[7][r])));
        for (int o = 1; o < 16; o <<= 1) mx = fmaxf(mx, __shfl_xor(mx, o));
        float mn = fmaxf(m_i[r], mx);
        float al = __expf(m_i[r] - mn);
        m_i[r] = mn;
        float rs = 0.f;
#pragma unroll
        for (int n = 0; n < 8; n++) {
          float p = __expf(sacc[n][r] - mn);
          sacc[n][r] = p;
          rs += p;
        }
        for (int o = 1; o < 16; o <<= 1) rs += __shfl_xor(rs, o);
        l_i[r] = al * l_i[r] + rs;
#pragma unroll
        for (int n = 0; n < 4; n++) oacc[n][r] *= al;
      }
      // P pack into sigma layout (col = l15*8 + n): 4 cvt_pk + 1 b128 store per r
#pragma unroll
      for (int r = 0; r < 4; r++) {
        union { unsigned int u[4]; bf16x8 v8; } pk;
        pk.u[0] = cvt_pk_bf16(sacc[0][r], sacc[1][r]);
        pk.u[1] = cvt_pk_bf16(sacc[2][r], sacc[3][r]);
        pk.u[2] = cvt_pk_bf16(sacc[4][r], sacc[5][r]);
        pk.u[3] = cvt_pk_bf16(sacc[6][r], sacc[7][r]);
        *(bf16x8*)(Pt + (16 * w + quad * 4 + r) * 136 + l15 * 8) = pk.v8;
      }
      __syncthreads();  // Pt visible (conservative full barrier)
#pragma unroll
      for (int c = 0; c < 4; c++) {
        bf16x8 pf = *(const bf16x8*)(Pt + (16 * w + l15) * 136 + c * 32 + quad * 8);
#pragma unroll
        for (int n = 0; n < 4; n++) {
          bf16x8 vf = *(const bf16x8*)(Vt + (n * 16 + l15) * 136 + c * 32 + quad * 8);
          oacc[n] = __builtin_amdgcn_mfma_f32_16x16x32_bf16(pf, vf, oacc[n], 0, 0, 0);
        }
      }
      __syncthreads();  // all warps done reading Kt/Vt/Pt of tile kt
      if (kt < qt) {    // stage prefetched tile kt+1
        *(bf16x8*)(Kt + krow * 72 + kq) = kv[0];
        *(bf16x8*)(Kt + krow * 72 + kq + 8) = kv[1];
#pragma unroll
        for (int j = 0; j < 2; j++) {
          const int ch = kc8 * 2 + j;
          u16* vb = Vt + dr * 136 + (ch & 1) * 64 + (ch >> 1);
#pragma unroll
          for (int e = 0; e < 8; e++) vb[e * 8] = (u16)vv[j][e];
        }
      }
      __syncthreads();  // staged tile visible
    }
    for (int n = 0; n < 4; n++)
      for (int r = 0; r < 4; r++) {
        int row = q0 + 16 * w + quad * 4 + r;
        out[(size_t)(b * SS + row) * EE + h * DD + n * 16 + l15] = f2b(oacc[n][r] / l_i[r]);
      }
  }
}

extern "C" void kernel_launch(void* const* d_in, const int* in_sizes, int n_in,
                              void* d_out, int out_size, void* d_ws, size_t ws_size,
                              hipStream_t stream) {
  const float* x       = (const float*)d_in[0];
  const float* ln_w    = (const float*)d_in[1];
  const float* ln_b    = (const float*)d_in[2];
  const float* qkv_w   = (const float*)d_in[3];
  const float* qkv_b   = (const float*)d_in[4];
  const float* qk_s    = (const float*)d_in[5];
  const float* out_w   = (const float*)d_in[6];
  const float* out_b   = (const float*)d_in[7];
  const float* inv_frq = (const float*)d_in[8];

  // ws (33.55 MB): xn bf16 [8.39 MB] | qkv bf16 [25.17 MB]
  u16* ws   = (u16*)d_ws;
  u16* xn   = ws;                               // 4096*1024 (LN out, later attn out)
  u16* qkv  = ws + (size_t)4096 * 1024;         // 4096*3072 (q,k normalized in place)
  // d_out is fp32 [16.78 MB]; stage bf16 scratch inside it while it's dead:
  u16* wq_b = (u16*)d_out;                      // [0, 6.29 MB): bf16 qkv_w
  float2* cs_tab = (float2*)((char*)d_out + 6291456);  // [6.29, 6.30 MB): cos/sin table
  u16* vt   = (u16*)d_out + (size_t)4194304;    // [8.39, 16.78 MB): bf16 V^T

  k_prep<<<7172, 256, 0, stream>>>(qkv_w, wq_b, inv_frq, cs_tab, x, ln_w, ln_b, xn);
  k_gemm_b<<<dim3(24, 32), 256, 0, stream>>>(xn, wq_b, qkv_b, qkv, 4096, 3072, 1024);
  k_rotv<<<4096, 256, 0, stream>>>(qkv, cs_tab, qk_s, vt);
  k_attn<<<dim3(8, 32), 512, 0, stream>>>(qkv, vt, xn);
  k_gemm_fw<<<dim3(8, 64), 256, 0, stream>>>(xn, out_w, out_b, (float*)d_out, 4096, 1024, 1024);
}

// Round 9
// 218.976 us; speedup vs baseline: 1.2288x; 1.0570x over previous
//
#include <hip/hip_runtime.h>

typedef unsigned short u16;
typedef __attribute__((ext_vector_type(8))) short bf16x8;   // 8 bf16 in 4 VGPRs (MFMA A/B frag)
typedef __attribute__((ext_vector_type(4))) float f32x4;    // MFMA C/D frag

#define SS 2048
#define EE 1024
#define HH 16
#define DD 64

__device__ __forceinline__ float b2f(u16 u) {
  union { unsigned int i; float f; } v; v.i = ((unsigned int)u) << 16; return v.f;
}
__device__ __forceinline__ u16 f2b(float f) {
  union { float f; unsigned int i; } v; v.f = f;
  unsigned int i = v.i;
  return (u16)((i + 0x7FFFu + ((i >> 16) & 1u)) >> 16);  // RNE
}
__device__ __forceinline__ unsigned int cvt_pk_bf16(float lo, float hi) {
  unsigned int r;
  asm("v_cvt_pk_bf16_f32 %0, %1, %2" : "=v"(r) : "v"(lo), "v"(hi));  // RNE pack, low=lo
  return r;
}

// async global->LDS, 16B per lane (m97 pattern; LDS dest = wave-uniform base + lane*16)
#define GLD16(g, l)                                                         \
  __builtin_amdgcn_global_load_lds(                                         \
      (const __attribute__((address_space(1))) unsigned int*)(g),           \
      (__attribute__((address_space(3))) unsigned int*)(l), 16, 0, 0)

// ---------------- fused prep: qkv_w cvt | trig table | LayerNorm ----------------
// blocks [0,3072): cvt qkv_w -> bf16; [3072,3076): cos/sin table; [3076,7172): LN rows
__global__ __launch_bounds__(256) void k_prep(const float* __restrict__ qkv_w,
                                              u16* __restrict__ wq_b,
                                              const float* __restrict__ inv_freq,
                                              float2* __restrict__ cs,
                                              const float* __restrict__ x,
                                              const float* __restrict__ lw,
                                              const float* __restrict__ lb,
                                              u16* __restrict__ xn) {
  const int bx = blockIdx.x, t = threadIdx.x;
  if (bx < 3072) {
    const int i = bx * 256 + t;
    float4 v = ((const float4*)qkv_w)[i];
    ushort4 o;
    o.x = f2b(v.x); o.y = f2b(v.y); o.z = f2b(v.z); o.w = f2b(v.w);
    ((ushort4*)wq_b)[i] = o;
    return;
  }
  if (bx < 3076) {
    const int i = (bx - 3072) * 256 + t;
    float th = 2048.0f * inv_freq[i];
    cs[i] = make_float2(cosf(th), sinf(th));
    return;
  }
  const int row = bx - 3076;
  float4 v = ((const float4*)(x + (size_t)row * EE))[t];
  float f0 = v.x, f1 = v.y, f2 = v.z, f3 = v.w;
  float s = f0 + f1 + f2 + f3;
  float ss = f0 * f0 + f1 * f1 + f2 * f2 + f3 * f3;
  for (int o = 1; o < 64; o <<= 1) { s += __shfl_xor(s, o); ss += __shfl_xor(ss, o); }
  __shared__ float red[8];
  int w = t >> 6;
  if ((t & 63) == 0) { red[w] = s; red[4 + w] = ss; }
  __syncthreads();
  s = red[0] + red[1] + red[2] + red[3];
  ss = red[4] + red[5] + red[6] + red[7];
  float mu = s * (1.0f / 1024.0f);
  float var = ss * (1.0f / 1024.0f) - mu * mu;
  float rstd = rsqrtf(var + 1e-5f);
  float4 wv = ((const float4*)lw)[t];
  float4 bv = ((const float4*)lb)[t];
  ushort4 o;
  o.x = f2b((f0 - mu) * rstd * wv.x + bv.x);
  o.y = f2b((f1 - mu) * rstd * wv.y + bv.y);
  o.z = f2b((f2 - mu) * rstd * wv.z + bv.z);
  o.w = f2b((f3 - mu) * rstd * wv.w + bv.w);
  ((ushort4*)(xn + (size_t)row * EE))[t] = o;
}

// ---- MFMA GEMM  C[M,N] = A[M,K] * W[N,K]^T + bias (bf16 A and W) ----
// m97 structure: 128x128 tile, BK=32, linear LDS, global_load_lds x16
__global__ __launch_bounds__(256) void k_gemm_b(const u16* __restrict__ A,
                                                const u16* __restrict__ W,
                                                const float* __restrict__ bias,
                                                u16* __restrict__ C,
                                                int M, int N, int K) {
  __shared__ __align__(16) u16 As[128 * 32];
  __shared__ __align__(16) u16 Ws[128 * 32];
  const int t = threadIdx.x;
  const int m0 = blockIdx.y * 128, n0 = blockIdx.x * 128;
  const int lane = t & 63, w = t >> 6, quad = lane >> 4, l15 = lane & 15;
  const int wm = (w & 1) * 64, wn = (w >> 1) * 64;

  f32x4 zero4 = {0.f, 0.f, 0.f, 0.f};
  f32x4 acc[4][4];
  for (int mi = 0; mi < 4; mi++)
    for (int ni = 0; ni < 4; ni++) acc[mi][ni] = zero4;

  const u16* Ag = A + (size_t)(m0 + (t >> 2)) * K + (t & 3) * 8;
  const u16* Wg = W + (size_t)(n0 + (t >> 2)) * K + (t & 3) * 8;
  const size_t rowskip = (size_t)64 * K;

  for (int k0 = 0; k0 < K; k0 += 32) {
    GLD16(Ag + k0, As + t * 8);
    GLD16(Ag + rowskip + k0, As + 2048 + t * 8);
    GLD16(Wg + k0, Ws + t * 8);
    GLD16(Wg + rowskip + k0, Ws + 2048 + t * 8);
    __syncthreads();
    bf16x8 af[4], wf[4];
#pragma unroll
    for (int i = 0; i < 4; i++) {
      af[i] = *(const bf16x8*)(As + (wm + i * 16 + l15) * 32 + quad * 8);
      wf[i] = *(const bf16x8*)(Ws + (wn + i * 16 + l15) * 32 + quad * 8);
    }
#pragma unroll
    for (int mi = 0; mi < 4; mi++)
#pragma unroll
      for (int ni = 0; ni < 4; ni++)
        acc[mi][ni] = __builtin_amdgcn_mfma_f32_16x16x32_bf16(af[mi], wf[ni], acc[mi][ni], 0, 0, 0);
    __syncthreads();
  }
  for (int mi = 0; mi < 4; mi++)
    for (int ni = 0; ni < 4; ni++) {
      int col = n0 + wn + ni * 16 + l15;
      float bb = bias[col];
      for (int r = 0; r < 4; r++) {
        int grow = m0 + wm + mi * 16 + quad * 4 + r;
        C[(size_t)grow * N + col] = f2b(acc[mi][ni][r] + bb);
      }
    }
}

// ---- MFMA GEMM with fp32 W (converted in-flight; replaces k_cvt + bf16 gemm_f) ----
// 64x128 tile: As via GLD16; W fp32 reg-staged -> cvt_pk -> linear b128 ds_write
__global__ __launch_bounds__(256) void k_gemm_fw(const u16* __restrict__ A,
                                                 const float* __restrict__ W,
                                                 const float* __restrict__ bias,
                                                 float* __restrict__ C,
                                                 int M, int N, int K) {
  __shared__ __align__(16) u16 As[64 * 32];
  __shared__ __align__(16) u16 Ws[128 * 32];
  const int t = threadIdx.x;
  const int m0 = blockIdx.y * 64, n0 = blockIdx.x * 128;
  const int lane = t & 63, w = t >> 6, quad = lane >> 4, l15 = lane & 15;
  const int wm = (w & 1) * 32, wn = (w >> 1) * 64;

  f32x4 zero4 = {0.f, 0.f, 0.f, 0.f};
  f32x4 acc[2][4];
  for (int mi = 0; mi < 2; mi++)
    for (int ni = 0; ni < 4; ni++) acc[mi][ni] = zero4;

  const u16* Ag = A + (size_t)(m0 + (t >> 2)) * K + (t & 3) * 8;
  const float* Wg0 = W + (size_t)(n0 + (t >> 2)) * K + (t & 3) * 8;
  const float* Wg1 = Wg0 + (size_t)64 * K;

  for (int k0 = 0; k0 < K; k0 += 32) {
    GLD16(Ag + k0, As + t * 8);
    float4 wa = *(const float4*)(Wg0 + k0);
    float4 wb = *(const float4*)(Wg0 + k0 + 4);
    float4 wc = *(const float4*)(Wg1 + k0);
    float4 wd = *(const float4*)(Wg1 + k0 + 4);
    union { unsigned int u[4]; bf16x8 v8; } p0, p1;
    p0.u[0] = cvt_pk_bf16(wa.x, wa.y); p0.u[1] = cvt_pk_bf16(wa.z, wa.w);
    p0.u[2] = cvt_pk_bf16(wb.x, wb.y); p0.u[3] = cvt_pk_bf16(wb.z, wb.w);
    p1.u[0] = cvt_pk_bf16(wc.x, wc.y); p1.u[1] = cvt_pk_bf16(wc.z, wc.w);
    p1.u[2] = cvt_pk_bf16(wd.x, wd.y); p1.u[3] = cvt_pk_bf16(wd.z, wd.w);
    *(bf16x8*)(Ws + t * 8) = p0.v8;         // rows 0..63, linear (conflict-free)
    *(bf16x8*)(Ws + 2048 + t * 8) = p1.v8;  // rows 64..127
    __syncthreads();
    bf16x8 af[2], wf[4];
#pragma unroll
    for (int i = 0; i < 2; i++)
      af[i] = *(const bf16x8*)(As + (wm + i * 16 + l15) * 32 + quad * 8);
#pragma unroll
    for (int i = 0; i < 4; i++)
      wf[i] = *(const bf16x8*)(Ws + (wn + i * 16 + l15) * 32 + quad * 8);
#pragma unroll
    for (int mi = 0; mi < 2; mi++)
#pragma unroll
      for (int ni = 0; ni < 4; ni++)
        acc[mi][ni] = __builtin_amdgcn_mfma_f32_16x16x32_bf16(af[mi], wf[ni], acc[mi][ni], 0, 0, 0);
    __syncthreads();
  }
  for (int mi = 0; mi < 2; mi++)
    for (int ni = 0; ni < 4; ni++) {
      int col = n0 + wn + ni * 16 + l15;
      float bb = bias[col];
      for (int r = 0; r < 4; r++) {
        int grow = m0 + wm + mi * 16 + quad * 4 + r;
        C[(size_t)grow * N + col] = acc[mi][ni][r] + bb;
      }
    }
}

// ------ fused: rotate+l2norm+scale (all 4096 rows) | V transpose (blocks < 1024) ------
__global__ __launch_bounds__(256) void k_rotv(u16* __restrict__ qkv,
                                              const float2* __restrict__ cs_tab,
                                              const float* __restrict__ scale_p,
                                              u16* __restrict__ vt) {
  __shared__ float qf[1024];
  __shared__ float kf[1024];
  __shared__ __align__(16) u16 tile[64 * 72];
  const int row = blockIdx.x, t = threadIdx.x;
  {
    u16* qr = qkv + (size_t)row * 3072;
    u16* kr = qr + 1024;
    ushort4 qv = ((const ushort4*)qr)[t];
    ushort4 kv = ((const ushort4*)kr)[t];
    *(float4*)(qf + 4 * t) = make_float4(b2f(qv.x), b2f(qv.y), b2f(qv.z), b2f(qv.w));
    *(float4*)(kf + 4 * t) = make_float4(b2f(kv.x), b2f(kv.y), b2f(kv.z), b2f(kv.w));
    __syncthreads();
    const float scale = scale_p[0];
    float rq[4], rk[4];
#pragma unroll
    for (int u = 0; u < 4; u++) {
      int j = 4 * t + u;
      float2 cs = cs_tab[j];
      float qrot = (j < 512) ? -qf[2 * j + 1] : qf[2 * (j - 512)];
      float krot = (j < 512) ? -kf[2 * j + 1] : kf[2 * (j - 512)];
      rq[u] = qf[j] * cs.x + qrot * cs.y;
      rk[u] = kf[j] * cs.x + krot * cs.y;
    }
    float ssq = rq[0] * rq[0] + rq[1] * rq[1] + rq[2] * rq[2] + rq[3] * rq[3];
    float ssk = rk[0] * rk[0] + rk[1] * rk[1] + rk[2] * rk[2] + rk[3] * rk[3];
    for (int o = 1; o < 16; o <<= 1) { ssq += __shfl_xor(ssq, o); ssk += __shfl_xor(ssk, o); }
    float qs = scale / fmaxf(sqrtf(ssq), 1e-12f);
    float ks = scale / fmaxf(sqrtf(ssk), 1e-12f);
    ushort4 qo, ko;
    qo.x = f2b(rq[0] * qs); qo.y = f2b(rq[1] * qs); qo.z = f2b(rq[2] * qs); qo.w = f2b(rq[3] * qs);
    ko.x = f2b(rk[0] * ks); ko.y = f2b(rk[1] * ks); ko.z = f2b(rk[2] * ks); ko.w = f2b(rk[3] * ks);
    ((ushort4*)qr)[t] = qo;
    ((ushort4*)kr)[t] = ko;
  }
  if (row >= 1024) return;
  // ---- V transpose job (reads V section: untouched by the rotnorm phase) ----
  const int st = row & 31, bh = row >> 5;
  const int b = bh >> 4, h = bh & 15;
  const int s0 = st * 64;
  const int si = t >> 2, dc = t & 3;
  __syncthreads();  // LDS reuse safety (qf/kf reads done before tile writes)
  const u16* src = qkv + (size_t)(b * SS + s0 + si) * 3072 + 2048 + h * DD;
  bf16x8 v0 = *(const bf16x8*)(src + dc * 8);
  bf16x8 v1 = *(const bf16x8*)(src + (dc + 4) * 8);
#pragma unroll
  for (int u = 0; u < 8; u++) tile[(dc * 8 + u) * 72 + si] = (u16)v0[u];
#pragma unroll
  for (int u = 0; u < 8; u++) tile[((dc + 4) * 8 + u) * 72 + si] = (u16)v1[u];
  __syncthreads();
#pragma unroll
  for (int it = 0; it < 2; it++) {
    int idx = t + it * 256;
    int d = idx >> 3, ch = idx & 7;
    bf16x8 o = *(const bf16x8*)(tile + d * 72 + ch * 8);
    *(bf16x8*)(vt + (size_t)(bh * DD + d) * SS + s0 + ch * 8) = o;
  }
}

// ---------------- causal flash attention (MFMA, swapped QK^T) ----------------
// QBLK=128 via 8 warps; KBLK=128; paired q-tiles (bx, 15-bx): uniform 17 iters.
// SWAPPED QK^T: sacc[n] = mfma(kfrag, qf) -> S^T: lane (quad,l15) holds
// S[k=16n+4quad+r][q=16w+l15] — one q-row per lane. Softmax row-reduce =
// in-register tree + TWO shfl_xor (16,32). P-pack k-contiguous (cvt_pk -> b64).
// al/l live at lane l15=q-row; O rows q=quad*4+r -> shfl from lane 20*quad+r.
// FIX vs round 8: Pt/Vt row stride 136 u16 (272 B) — rows hold 128 k-values;
// stride-72 rows overflowed (the round-8 absmax failure). All b64/b128 offsets
// stay 16B-aligned (272 = 17*16).
__global__ __launch_bounds__(512) void k_attn(const u16* __restrict__ qkv,
                                              const u16* __restrict__ vt,
                                              u16* __restrict__ out) {
  __shared__ __align__(16) u16 Kt[128 * 72];    // K rows (d=0..63 + pad)
  __shared__ __align__(16) u16 Vt[64 * 136];    // V^T rows d, k=0..127 + pad
  __shared__ __align__(16) u16 Pt[128 * 136];   // P rows q, k=0..127 + pad
  const int bh = blockIdx.y;
  const int b = bh >> 4, h = bh & 15;
  const int t = threadIdx.x, w = t >> 6, lane = t & 63, quad = lane >> 4, l15 = lane & 15;
  const int krow = t >> 2, kq = (t & 3) * 16;  // K staging: row 0..127, 16-u16 quarter
  const int dr = t >> 3, kc8 = t & 7;          // V staging: d-row 0..63, 16-k eighth
  const int srcl = (lane & 48) + ((lane >> 4) << 2);  // 20*quad: state-holder base lane
  const u16* kn = qkv + 1024;
  f32x4 zero4 = {0.f, 0.f, 0.f, 0.f};

  for (int rep = 0; rep < 2; rep++) {
    const int qt = rep ? 15 - (int)blockIdx.x : (int)blockIdx.x;  // 128-row q-tile
    const int q0 = qt * 128;

    bf16x8 qf[2];
    {
      const u16* qrow = qkv + (size_t)(b * SS + q0 + 16 * w + l15) * 3072 + h * DD;
      qf[0] = *(const bf16x8*)(qrow + quad * 8);
      qf[1] = *(const bf16x8*)(qrow + 32 + quad * 8);
    }
    f32x4 oacc[4];
    for (int n = 0; n < 4; n++) oacc[n] = zero4;
    float m_i = -1e30f, l_i = 0.f;   // per-lane: state for q-row 16w+l15

    bf16x8 kv[2], vv[2];
    // prologue: load & stage tile kt=0
    {
      const u16* krg = kn + (size_t)(b * SS + krow) * 3072 + h * DD + kq;
      kv[0] = *(const bf16x8*)(krg);
      kv[1] = *(const bf16x8*)(krg + 8);
      const u16* vrg = vt + (size_t)(bh * DD + dr) * SS + kc8 * 16;
      vv[0] = *(const bf16x8*)(vrg);
      vv[1] = *(const bf16x8*)(vrg + 8);
    }
    __syncthreads();  // previous rep's readers done before overwriting buffers
    *(bf16x8*)(Kt + krow * 72 + kq) = kv[0];
    *(bf16x8*)(Kt + krow * 72 + kq + 8) = kv[1];
    *(bf16x8*)(Vt + dr * 136 + kc8 * 16) = vv[0];
    *(bf16x8*)(Vt + dr * 136 + kc8 * 16 + 8) = vv[1];
    __syncthreads();

    for (int kt = 0; kt <= qt; kt++) {
      if (kt < qt) {  // prefetch next tile into regs; staged after bottom barrier
        const int k0n = (kt + 1) * 128;
        const u16* krg = kn + (size_t)(b * SS + k0n + krow) * 3072 + h * DD + kq;
        kv[0] = *(const bf16x8*)(krg);
        kv[1] = *(const bf16x8*)(krg + 8);
        const u16* vrg = vt + (size_t)(bh * DD + dr) * SS + k0n + kc8 * 16;
        vv[0] = *(const bf16x8*)(vrg);
        vv[1] = *(const bf16x8*)(vrg + 8);
      }
      // ---- swapped QK^T: A = K-group (16 k-rows), B = Q ----
      f32x4 sacc[8];
#pragma unroll
      for (int n = 0; n < 8; n++) {
        sacc[n] = zero4;
#pragma unroll
        for (int c = 0; c < 2; c++) {
          bf16x8 kfrag = *(const bf16x8*)(Kt + (n * 16 + l15) * 72 + c * 32 + quad * 8);
          sacc[n] = __builtin_amdgcn_mfma_f32_16x16x32_bf16(kfrag, qf[c], sacc[n], 0, 0, 0);
        }
      }
      if (kt == qt) {  // diagonal: mask k > q-row-in-tile; k = 16n+4quad+r, q = 16w+l15
        const int qrow = 16 * w + l15, kbase = 4 * quad;
#pragma unroll
        for (int n = 0; n < 8; n++)
#pragma unroll
          for (int r = 0; r < 4; r++)
            if (16 * n + kbase + r > qrow) sacc[n][r] = -1e30f;
      }
      // ---- lane-local softmax for q-row 16w+l15 ----
      float mx = -1e30f;
#pragma unroll
      for (int n = 0; n < 8; n++)
#pragma unroll
        for (int r = 0; r < 4; r++) mx = fmaxf(mx, sacc[n][r]);
      mx = fmaxf(mx, __shfl_xor(mx, 16));
      mx = fmaxf(mx, __shfl_xor(mx, 32));
      float mn = fmaxf(m_i, mx);
      float al = __expf(m_i - mn);
      m_i = mn;
      float rs = 0.f;
#pragma unroll
      for (int n = 0; n < 8; n++)
#pragma unroll
        for (int r = 0; r < 4; r++) {
          float p = __expf(sacc[n][r] - mn);
          sacc[n][r] = p;
          rs += p;
        }
      rs += __shfl_xor(rs, 16);
      rs += __shfl_xor(rs, 32);
      l_i = al * l_i + rs;
      // broadcast al to O-row holders (O row q = quad*4+r; state at lane 20*quad+r)
      float alr[4];
#pragma unroll
      for (int r = 0; r < 4; r++) alr[r] = __shfl(al, srcl + r);
#pragma unroll
      for (int n = 0; n < 4; n++)
#pragma unroll
        for (int r = 0; r < 4; r++) oacc[n][r] *= alr[r];
      // ---- P pack: k-contiguous pairs -> b64 at Pt[q][k] (linear k layout) ----
#pragma unroll
      for (int n = 0; n < 8; n++) {
        uint2 pk;
        pk.x = cvt_pk_bf16(sacc[n][0], sacc[n][1]);
        pk.y = cvt_pk_bf16(sacc[n][2], sacc[n][3]);
        *(uint2*)(Pt + (16 * w + l15) * 136 + 16 * n + 4 * quad) = pk;
      }
      __syncthreads();  // Pt visible (conservative full barrier)
      // ---- PV: A = P[q][k] (standard), B = V^T[d][k] rows (standard) ----
#pragma unroll
      for (int c = 0; c < 4; c++) {
        bf16x8 pf = *(const bf16x8*)(Pt + (16 * w + l15) * 136 + c * 32 + quad * 8);
#pragma unroll
        for (int n = 0; n < 4; n++) {
          bf16x8 vf = *(const bf16x8*)(Vt + (n * 16 + l15) * 136 + c * 32 + quad * 8);
          oacc[n] = __builtin_amdgcn_mfma_f32_16x16x32_bf16(pf, vf, oacc[n], 0, 0, 0);
        }
      }
      __syncthreads();  // all warps done reading Kt/Vt/Pt of tile kt
      if (kt < qt) {    // stage prefetched tile kt+1
        *(bf16x8*)(Kt + krow * 72 + kq) = kv[0];
        *(bf16x8*)(Kt + krow * 72 + kq + 8) = kv[1];
        *(bf16x8*)(Vt + dr * 136 + kc8 * 16) = vv[0];
        *(bf16x8*)(Vt + dr * 136 + kc8 * 16 + 8) = vv[1];
      }
      __syncthreads();  // staged tile visible
    }
    float lr[4];
#pragma unroll
    for (int r = 0; r < 4; r++) lr[r] = __shfl(l_i, srcl + r);
    for (int n = 0; n < 4; n++)
      for (int r = 0; r < 4; r++) {
        int row = q0 + 16 * w + quad * 4 + r;
        out[(size_t)(b * SS + row) * EE + h * DD + n * 16 + l15] = f2b(oacc[n][r] / lr[r]);
      }
  }
}

extern "C" void kernel_launch(void* const* d_in, const int* in_sizes, int n_in,
                              void* d_out, int out_size, void* d_ws, size_t ws_size,
                              hipStream_t stream) {
  const float* x       = (const float*)d_in[0];
  const float* ln_w    = (const float*)d_in[1];
  const float* ln_b    = (const float*)d_in[2];
  const float* qkv_w   = (const float*)d_in[3];
  const float* qkv_b   = (const float*)d_in[4];
  const float* qk_s    = (const float*)d_in[5];
  const float* out_w   = (const float*)d_in[6];
  const float* out_b   = (const float*)d_in[7];
  const float* inv_frq = (const float*)d_in[8];

  // ws (33.55 MB): xn bf16 [8.39 MB] | qkv bf16 [25.17 MB]
  u16* ws   = (u16*)d_ws;
  u16* xn   = ws;                               // 4096*1024 (LN out, later attn out)
  u16* qkv  = ws + (size_t)4096 * 1024;         // 4096*3072 (q,k normalized in place)
  // d_out is fp32 [16.78 MB]; stage bf16 scratch inside it while it's dead:
  u16* wq_b = (u16*)d_out;                      // [0, 6.29 MB): bf16 qkv_w
  float2* cs_tab = (float2*)((char*)d_out + 6291456);  // [6.29, 6.30 MB): cos/sin table
  u16* vt   = (u16*)d_out + (size_t)4194304;    // [8.39, 16.78 MB): bf16 V^T

  k_prep<<<7172, 256, 0, stream>>>(qkv_w, wq_b, inv_frq, cs_tab, x, ln_w, ln_b, xn);
  k_gemm_b<<<dim3(24, 32), 256, 0, stream>>>(xn, wq_b, qkv_b, qkv, 4096, 3072, 1024);
  k_rotv<<<4096, 256, 0, stream>>>(qkv, cs_tab, qk_s, vt);
  k_attn<<<dim3(8, 32), 512, 0, stream>>>(qkv, vt, xn);
  k_gemm_fw<<<dim3(8, 64), 256, 0, stream>>>(xn, out_w, out_b, (float*)d_out, 4096, 1024, 1024);
}

// Round 10
// 216.296 us; speedup vs baseline: 1.2440x; 1.0124x over previous
//
#include <hip/hip_runtime.h>

typedef unsigned short u16;
typedef __attribute__((ext_vector_type(8))) short bf16x8;   // 8 bf16 in 4 VGPRs (MFMA A/B frag)
typedef __attribute__((ext_vector_type(4))) float f32x4;    // MFMA C/D frag

#define SS 2048
#define EE 1024
#define HH 16
#define DD 64

__device__ __forceinline__ float b2f(u16 u) {
  union { unsigned int i; float f; } v; v.i = ((unsigned int)u) << 16; return v.f;
}
__device__ __forceinline__ u16 f2b(float f) {
  union { float f; unsigned int i; } v; v.f = f;
  unsigned int i = v.i;
  return (u16)((i + 0x7FFFu + ((i >> 16) & 1u)) >> 16);  // RNE
}
__device__ __forceinline__ unsigned int cvt_pk_bf16(float lo, float hi) {
  unsigned int r;
  asm("v_cvt_pk_bf16_f32 %0, %1, %2" : "=v"(r) : "v"(lo), "v"(hi));  // RNE pack, low=lo
  return r;
}

// async global->LDS, 16B per lane (m97 pattern; LDS dest = wave-uniform base + lane*16)
#define GLD16(g, l)                                                         \
  __builtin_amdgcn_global_load_lds(                                         \
      (const __attribute__((address_space(1))) unsigned int*)(g),           \
      (__attribute__((address_space(3))) unsigned int*)(l), 16, 0, 0)

// ---------------- fused prep: qkv_w cvt | trig table | LayerNorm ----------------
// blocks [0,3072): cvt qkv_w -> bf16; [3072,3076): cos/sin table; [3076,7172): LN rows
__global__ __launch_bounds__(256) void k_prep(const float* __restrict__ qkv_w,
                                              u16* __restrict__ wq_b,
                                              const float* __restrict__ inv_freq,
                                              float2* __restrict__ cs,
                                              const float* __restrict__ x,
                                              const float* __restrict__ lw,
                                              const float* __restrict__ lb,
                                              u16* __restrict__ xn) {
  const int bx = blockIdx.x, t = threadIdx.x;
  if (bx < 3072) {
    const int i = bx * 256 + t;
    float4 v = ((const float4*)qkv_w)[i];
    ushort4 o;
    o.x = f2b(v.x); o.y = f2b(v.y); o.z = f2b(v.z); o.w = f2b(v.w);
    ((ushort4*)wq_b)[i] = o;
    return;
  }
  if (bx < 3076) {
    const int i = (bx - 3072) * 256 + t;
    float th = 2048.0f * inv_freq[i];
    cs[i] = make_float2(cosf(th), sinf(th));
    return;
  }
  const int row = bx - 3076;
  float4 v = ((const float4*)(x + (size_t)row * EE))[t];
  float f0 = v.x, f1 = v.y, f2 = v.z, f3 = v.w;
  float s = f0 + f1 + f2 + f3;
  float ss = f0 * f0 + f1 * f1 + f2 * f2 + f3 * f3;
  for (int o = 1; o < 64; o <<= 1) { s += __shfl_xor(s, o); ss += __shfl_xor(ss, o); }
  __shared__ float red[8];
  int w = t >> 6;
  if ((t & 63) == 0) { red[w] = s; red[4 + w] = ss; }
  __syncthreads();
  s = red[0] + red[1] + red[2] + red[3];
  ss = red[4] + red[5] + red[6] + red[7];
  float mu = s * (1.0f / 1024.0f);
  float var = ss * (1.0f / 1024.0f) - mu * mu;
  float rstd = rsqrtf(var + 1e-5f);
  float4 wv = ((const float4*)lw)[t];
  float4 bv = ((const float4*)lb)[t];
  ushort4 o;
  o.x = f2b((f0 - mu) * rstd * wv.x + bv.x);
  o.y = f2b((f1 - mu) * rstd * wv.y + bv.y);
  o.z = f2b((f2 - mu) * rstd * wv.z + bv.z);
  o.w = f2b((f3 - mu) * rstd * wv.w + bv.w);
  ((ushort4*)(xn + (size_t)row * EE))[t] = o;
}

// ---- MFMA GEMM  C[M,N] = A[M,K] * W[N,K]^T + bias (bf16 A and W) ----
// m97 structure: 128x128 tile, BK=32, linear LDS, global_load_lds x16
// XCD-aware bijective block swizzle (T1): nwg % 8 == 0 for all launches here.
__global__ __launch_bounds__(256) void k_gemm_b(const u16* __restrict__ A,
                                                const u16* __restrict__ W,
                                                const float* __restrict__ bias,
                                                u16* __restrict__ C,
                                                int M, int N, int K) {
  __shared__ __align__(16) u16 As[128 * 32];
  __shared__ __align__(16) u16 Ws[128 * 32];
  const int t = threadIdx.x;
  const int flat = blockIdx.y * gridDim.x + blockIdx.x;
  const int nwg8 = (int)(gridDim.x * gridDim.y) >> 3;
  const int sw = (flat & 7) * nwg8 + (flat >> 3);
  const int m0 = (sw / (int)gridDim.x) * 128, n0 = (sw % (int)gridDim.x) * 128;
  const int lane = t & 63, w = t >> 6, quad = lane >> 4, l15 = lane & 15;
  const int wm = (w & 1) * 64, wn = (w >> 1) * 64;

  f32x4 zero4 = {0.f, 0.f, 0.f, 0.f};
  f32x4 acc[4][4];
  for (int mi = 0; mi < 4; mi++)
    for (int ni = 0; ni < 4; ni++) acc[mi][ni] = zero4;

  const u16* Ag = A + (size_t)(m0 + (t >> 2)) * K + (t & 3) * 8;
  const u16* Wg = W + (size_t)(n0 + (t >> 2)) * K + (t & 3) * 8;
  const size_t rowskip = (size_t)64 * K;

  for (int k0 = 0; k0 < K; k0 += 32) {
    GLD16(Ag + k0, As + t * 8);
    GLD16(Ag + rowskip + k0, As + 2048 + t * 8);
    GLD16(Wg + k0, Ws + t * 8);
    GLD16(Wg + rowskip + k0, Ws + 2048 + t * 8);
    __syncthreads();
    bf16x8 af[4], wf[4];
#pragma unroll
    for (int i = 0; i < 4; i++) {
      af[i] = *(const bf16x8*)(As + (wm + i * 16 + l15) * 32 + quad * 8);
      wf[i] = *(const bf16x8*)(Ws + (wn + i * 16 + l15) * 32 + quad * 8);
    }
#pragma unroll
    for (int mi = 0; mi < 4; mi++)
#pragma unroll
      for (int ni = 0; ni < 4; ni++)
        acc[mi][ni] = __builtin_amdgcn_mfma_f32_16x16x32_bf16(af[mi], wf[ni], acc[mi][ni], 0, 0, 0);
    __syncthreads();
  }
  for (int mi = 0; mi < 4; mi++)
    for (int ni = 0; ni < 4; ni++) {
      int col = n0 + wn + ni * 16 + l15;
      float bb = bias[col];
      for (int r = 0; r < 4; r++) {
        int grow = m0 + wm + mi * 16 + quad * 4 + r;
        C[(size_t)grow * N + col] = f2b(acc[mi][ni][r] + bb);
      }
    }
}

// ---- MFMA GEMM with fp32 W (converted in-flight; replaces k_cvt + bf16 gemm_f) ----
// 64x128 tile: As via GLD16; W fp32 reg-staged -> cvt_pk -> linear b128 ds_write
__global__ __launch_bounds__(256) void k_gemm_fw(const u16* __restrict__ A,
                                                 const float* __restrict__ W,
                                                 const float* __restrict__ bias,
                                                 float* __restrict__ C,
                                                 int M, int N, int K) {
  __shared__ __align__(16) u16 As[64 * 32];
  __shared__ __align__(16) u16 Ws[128 * 32];
  const int t = threadIdx.x;
  const int flat = blockIdx.y * gridDim.x + blockIdx.x;
  const int nwg8 = (int)(gridDim.x * gridDim.y) >> 3;
  const int sw = (flat & 7) * nwg8 + (flat >> 3);
  const int m0 = (sw / (int)gridDim.x) * 64, n0 = (sw % (int)gridDim.x) * 128;
  const int lane = t & 63, w = t >> 6, quad = lane >> 4, l15 = lane & 15;
  const int wm = (w & 1) * 32, wn = (w >> 1) * 64;

  f32x4 zero4 = {0.f, 0.f, 0.f, 0.f};
  f32x4 acc[2][4];
  for (int mi = 0; mi < 2; mi++)
    for (int ni = 0; ni < 4; ni++) acc[mi][ni] = zero4;

  const u16* Ag = A + (size_t)(m0 + (t >> 2)) * K + (t & 3) * 8;
  const float* Wg0 = W + (size_t)(n0 + (t >> 2)) * K + (t & 3) * 8;
  const float* Wg1 = Wg0 + (size_t)64 * K;

  for (int k0 = 0; k0 < K; k0 += 32) {
    GLD16(Ag + k0, As + t * 8);
    float4 wa = *(const float4*)(Wg0 + k0);
    float4 wb = *(const float4*)(Wg0 + k0 + 4);
    float4 wc = *(const float4*)(Wg1 + k0);
    float4 wd = *(const float4*)(Wg1 + k0 + 4);
    union { unsigned int u[4]; bf16x8 v8; } p0, p1;
    p0.u[0] = cvt_pk_bf16(wa.x, wa.y); p0.u[1] = cvt_pk_bf16(wa.z, wa.w);
    p0.u[2] = cvt_pk_bf16(wb.x, wb.y); p0.u[3] = cvt_pk_bf16(wb.z, wb.w);
    p1.u[0] = cvt_pk_bf16(wc.x, wc.y); p1.u[1] = cvt_pk_bf16(wc.z, wc.w);
    p1.u[2] = cvt_pk_bf16(wd.x, wd.y); p1.u[3] = cvt_pk_bf16(wd.z, wd.w);
    *(bf16x8*)(Ws + t * 8) = p0.v8;         // rows 0..63, linear (conflict-free)
    *(bf16x8*)(Ws + 2048 + t * 8) = p1.v8;  // rows 64..127
    __syncthreads();
    bf16x8 af[2], wf[4];
#pragma unroll
    for (int i = 0; i < 2; i++)
      af[i] = *(const bf16x8*)(As + (wm + i * 16 + l15) * 32 + quad * 8);
#pragma unroll
    for (int i = 0; i < 4; i++)
      wf[i] = *(const bf16x8*)(Ws + (wn + i * 16 + l15) * 32 + quad * 8);
#pragma unroll
    for (int mi = 0; mi < 2; mi++)
#pragma unroll
      for (int ni = 0; ni < 4; ni++)
        acc[mi][ni] = __builtin_amdgcn_mfma_f32_16x16x32_bf16(af[mi], wf[ni], acc[mi][ni], 0, 0, 0);
    __syncthreads();
  }
  for (int mi = 0; mi < 2; mi++)
    for (int ni = 0; ni < 4; ni++) {
      int col = n0 + wn + ni * 16 + l15;
      float bb = bias[col];
      for (int r = 0; r < 4; r++) {
        int grow = m0 + wm + mi * 16 + quad * 4 + r;
        C[(size_t)grow * N + col] = acc[mi][ni][r] + bb;
      }
    }
}

// ------ fused: rotate+l2norm+scale (all 4096 rows) | V transpose (blocks < 1024) ------
__global__ __launch_bounds__(256) void k_rotv(u16* __restrict__ qkv,
                                              const float2* __restrict__ cs_tab,
                                              const float* __restrict__ scale_p,
                                              u16* __restrict__ vt) {
  __shared__ float qf[1024];
  __shared__ float kf[1024];
  __shared__ __align__(16) u16 tile[64 * 72];
  const int row = blockIdx.x, t = threadIdx.x;
  {
    u16* qr = qkv + (size_t)row * 3072;
    u16* kr = qr + 1024;
    ushort4 qv = ((const ushort4*)qr)[t];
    ushort4 kv = ((const ushort4*)kr)[t];
    *(float4*)(qf + 4 * t) = make_float4(b2f(qv.x), b2f(qv.y), b2f(qv.z), b2f(qv.w));
    *(float4*)(kf + 4 * t) = make_float4(b2f(kv.x), b2f(kv.y), b2f(kv.z), b2f(kv.w));
    __syncthreads();
    const float scale = scale_p[0];
    float rq[4], rk[4];
#pragma unroll
    for (int u = 0; u < 4; u++) {
      int j = 4 * t + u;
      float2 cs = cs_tab[j];
      float qrot = (j < 512) ? -qf[2 * j + 1] : qf[2 * (j - 512)];
      float krot = (j < 512) ? -kf[2 * j + 1] : kf[2 * (j - 512)];
      rq[u] = qf[j] * cs.x + qrot * cs.y;
      rk[u] = kf[j] * cs.x + krot * cs.y;
    }
    float ssq = rq[0] * rq[0] + rq[1] * rq[1] + rq[2] * rq[2] + rq[3] * rq[3];
    float ssk = rk[0] * rk[0] + rk[1] * rk[1] + rk[2] * rk[2] + rk[3] * rk[3];
    for (int o = 1; o < 16; o <<= 1) { ssq += __shfl_xor(ssq, o); ssk += __shfl_xor(ssk, o); }
    float qs = scale / fmaxf(sqrtf(ssq), 1e-12f);
    float ks = scale / fmaxf(sqrtf(ssk), 1e-12f);
    ushort4 qo, ko;
    qo.x = f2b(rq[0] * qs); qo.y = f2b(rq[1] * qs); qo.z = f2b(rq[2] * qs); qo.w = f2b(rq[3] * qs);
    ko.x = f2b(rk[0] * ks); ko.y = f2b(rk[1] * ks); ko.z = f2b(rk[2] * ks); ko.w = f2b(rk[3] * ks);
    ((ushort4*)qr)[t] = qo;
    ((ushort4*)kr)[t] = ko;
  }
  if (row >= 1024) return;
  // ---- V transpose job (reads V section: untouched by the rotnorm phase) ----
  const int st = row & 31, bh = row >> 5;
  const int b = bh >> 4, h = bh & 15;
  const int s0 = st * 64;
  const int si = t >> 2, dc = t & 3;
  __syncthreads();  // LDS reuse safety (qf/kf reads done before tile writes)
  const u16* src = qkv + (size_t)(b * SS + s0 + si) * 3072 + 2048 + h * DD;
  bf16x8 v0 = *(const bf16x8*)(src + dc * 8);
  bf16x8 v1 = *(const bf16x8*)(src + (dc + 4) * 8);
#pragma unroll
  for (int u = 0; u < 8; u++) tile[(dc * 8 + u) * 72 + si] = (u16)v0[u];
#pragma unroll
  for (int u = 0; u < 8; u++) tile[((dc + 4) * 8 + u) * 72 + si] = (u16)v1[u];
  __syncthreads();
#pragma unroll
  for (int it = 0; it < 2; it++) {
    int idx = t + it * 256;
    int d = idx >> 3, ch = idx & 7;
    bf16x8 o = *(const bf16x8*)(tile + d * 72 + ch * 8);
    *(bf16x8*)(vt + (size_t)(bh * DD + d) * SS + s0 + ch * 8) = o;
  }
}

// ---------------- causal flash attention (MFMA, swapped QK^T) ----------------
// QBLK=128 via 8 warps; KBLK=128; paired q-tiles (bx, 15-bx): uniform 17 iters.
// SWAPPED QK^T: sacc[n] = mfma(kfrag, qf) -> S^T: lane (quad,l15) holds
// S[k=16n+4quad+r][q=16w+l15]. Lane-local softmax + 2 shfl_xor.
// Round-10 change: K/V LDS DOUBLE-BUFFER -> ONE barrier per iteration.
// Pt is warp-private (warp w writes and reads only rows [16w,16w+16)):
// lgkmcnt(0)+sched_barrier suffices (round-4/5-proven; round-8 fail was the
// stride-72 overflow, fixed in round 9). Stage(kt+1) targets buf^1 so it can
// never race reads of buf[cur]; the end-of-iter barrier protects the flip.
__global__ __launch_bounds__(512) void k_attn(const u16* __restrict__ qkv,
                                              const u16* __restrict__ vt,
                                              u16* __restrict__ out) {
  __shared__ __align__(16) u16 Kt[2][128 * 72];    // K rows (d=0..63 + pad)
  __shared__ __align__(16) u16 Vt[2][64 * 136];    // V^T rows d, k=0..127 + pad
  __shared__ __align__(16) u16 Pt[128 * 136];      // P rows q, k=0..127 + pad
  const int bh = blockIdx.y;
  const int b = bh >> 4, h = bh & 15;
  const int t = threadIdx.x, w = t >> 6, lane = t & 63, quad = lane >> 4, l15 = lane & 15;
  const int krow = t >> 2, kq = (t & 3) * 16;  // K staging: row 0..127, 16-u16 quarter
  const int dr = t >> 3, kc8 = t & 7;          // V staging: d-row 0..63, 16-k eighth
  const int srcl = (lane & 48) + ((lane >> 4) << 2);  // 20*quad: state-holder base lane
  const u16* kn = qkv + 1024;
  f32x4 zero4 = {0.f, 0.f, 0.f, 0.f};

  for (int rep = 0; rep < 2; rep++) {
    const int qt = rep ? 15 - (int)blockIdx.x : (int)blockIdx.x;  // 128-row q-tile
    const int q0 = qt * 128;

    bf16x8 qf[2];
    {
      const u16* qrow = qkv + (size_t)(b * SS + q0 + 16 * w + l15) * 3072 + h * DD;
      qf[0] = *(const bf16x8*)(qrow + quad * 8);
      qf[1] = *(const bf16x8*)(qrow + 32 + quad * 8);
    }
    f32x4 oacc[4];
    for (int n = 0; n < 4; n++) oacc[n] = zero4;
    float m_i = -1e30f, l_i = 0.f;   // per-lane: state for q-row 16w+l15

    bf16x8 kv[2], vv[2];
    // prologue: load & stage tile kt=0 into buf 0
    {
      const u16* krg = kn + (size_t)(b * SS + krow) * 3072 + h * DD + kq;
      kv[0] = *(const bf16x8*)(krg);
      kv[1] = *(const bf16x8*)(krg + 8);
      const u16* vrg = vt + (size_t)(bh * DD + dr) * SS + kc8 * 16;
      vv[0] = *(const bf16x8*)(vrg);
      vv[1] = *(const bf16x8*)(vrg + 8);
    }
    __syncthreads();  // previous rep fully done with LDS
    *(bf16x8*)(Kt[0] + krow * 72 + kq) = kv[0];
    *(bf16x8*)(Kt[0] + krow * 72 + kq + 8) = kv[1];
    *(bf16x8*)(Vt[0] + dr * 136 + kc8 * 16) = vv[0];
    *(bf16x8*)(Vt[0] + dr * 136 + kc8 * 16 + 8) = vv[1];
    __syncthreads();
    int cur = 0;

    for (int kt = 0; kt <= qt; kt++) {
      if (kt < qt) {  // prefetch next tile into regs; staged into buf^1 below
        const int k0n = (kt + 1) * 128;
        const u16* krg = kn + (size_t)(b * SS + k0n + krow) * 3072 + h * DD + kq;
        kv[0] = *(const bf16x8*)(krg);
        kv[1] = *(const bf16x8*)(krg + 8);
        const u16* vrg = vt + (size_t)(bh * DD + dr) * SS + k0n + kc8 * 16;
        vv[0] = *(const bf16x8*)(vrg);
        vv[1] = *(const bf16x8*)(vrg + 8);
      }
      const u16* Kc = Kt[cur];
      const u16* Vc = Vt[cur];
      // ---- swapped QK^T: A = K-group (16 k-rows), B = Q ----
      f32x4 sacc[8];
#pragma unroll
      for (int n = 0; n < 8; n++) {
        sacc[n] = zero4;
#pragma unroll
        for (int c = 0; c < 2; c++) {
          bf16x8 kfrag = *(const bf16x8*)(Kc + (n * 16 + l15) * 72 + c * 32 + quad * 8);
          sacc[n] = __builtin_amdgcn_mfma_f32_16x16x32_bf16(kfrag, qf[c], sacc[n], 0, 0, 0);
        }
      }
      if (kt == qt) {  // diagonal: mask k > q-row-in-tile; k = 16n+4quad+r, q = 16w+l15
        const int qrow = 16 * w + l15, kbase = 4 * quad;
#pragma unroll
        for (int n = 0; n < 8; n++)
#pragma unroll
          for (int r = 0; r < 4; r++)
            if (16 * n + kbase + r > qrow) sacc[n][r] = -1e30f;
      }
      // ---- lane-local softmax for q-row 16w+l15 ----
      float mx = -1e30f;
#pragma unroll
      for (int n = 0; n < 8; n++)
#pragma unroll
        for (int r = 0; r < 4; r++) mx = fmaxf(mx, sacc[n][r]);
      mx = fmaxf(mx, __shfl_xor(mx, 16));
      mx = fmaxf(mx, __shfl_xor(mx, 32));
      float mn = fmaxf(m_i, mx);
      float al = __expf(m_i - mn);
      m_i = mn;
      float rs = 0.f;
#pragma unroll
      for (int n = 0; n < 8; n++)
#pragma unroll
        for (int r = 0; r < 4; r++) {
          float p = __expf(sacc[n][r] - mn);
          sacc[n][r] = p;
          rs += p;
        }
      rs += __shfl_xor(rs, 16);
      rs += __shfl_xor(rs, 32);
      l_i = al * l_i + rs;
      // broadcast al to O-row holders (O row q = quad*4+r; state at lane 20*quad+r)
      float alr[4];
#pragma unroll
      for (int r = 0; r < 4; r++) alr[r] = __shfl(al, srcl + r);
#pragma unroll
      for (int n = 0; n < 4; n++)
#pragma unroll
        for (int r = 0; r < 4; r++) oacc[n][r] *= alr[r];
      // ---- P pack: k-contiguous pairs -> b64 at Pt[q][k] (linear k layout) ----
#pragma unroll
      for (int n = 0; n < 8; n++) {
        uint2 pk;
        pk.x = cvt_pk_bf16(sacc[n][0], sacc[n][1]);
        pk.y = cvt_pk_bf16(sacc[n][2], sacc[n][3]);
        *(uint2*)(Pt + (16 * w + l15) * 136 + 16 * n + 4 * quad) = pk;
      }
      // Pt warp-private: LDS completion only (rule 18: sched_barrier after wait)
      asm volatile("s_waitcnt lgkmcnt(0)" ::: "memory");
      __builtin_amdgcn_sched_barrier(0);
      // ---- PV: A = P[q][k], B = V^T[d][k] rows ----
#pragma unroll
      for (int c = 0; c < 4; c++) {
        bf16x8 pf = *(const bf16x8*)(Pt + (16 * w + l15) * 136 + c * 32 + quad * 8);
#pragma unroll
        for (int n = 0; n < 4; n++) {
          bf16x8 vf = *(const bf16x8*)(Vc + (n * 16 + l15) * 136 + c * 32 + quad * 8);
          oacc[n] = __builtin_amdgcn_mfma_f32_16x16x32_bf16(pf, vf, oacc[n], 0, 0, 0);
        }
      }
      if (kt < qt) {  // stage prefetched tile into the other buffer (no race: buf^1)
        *(bf16x8*)(Kt[cur ^ 1] + krow * 72 + kq) = kv[0];
        *(bf16x8*)(Kt[cur ^ 1] + krow * 72 + kq + 8) = kv[1];
        *(bf16x8*)(Vt[cur ^ 1] + dr * 136 + kc8 * 16) = vv[0];
        *(bf16x8*)(Vt[cur ^ 1] + dr * 136 + kc8 * 16 + 8) = vv[1];
      }
      __syncthreads();  // single barrier: buf[cur] readers done + buf^1 staged
      cur ^= 1;
    }
    float lr[4];
#pragma unroll
    for (int r = 0; r < 4; r++) lr[r] = __shfl(l_i, srcl + r);
    for (int n = 0; n < 4; n++)
      for (int r = 0; r < 4; r++) {
        int row = q0 + 16 * w + quad * 4 + r;
        out[(size_t)(b * SS + row) * EE + h * DD + n * 16 + l15] = f2b(oacc[n][r] / lr[r]);
      }
  }
}

extern "C" void kernel_launch(void* const* d_in, const int* in_sizes, int n_in,
                              void* d_out, int out_size, void* d_ws, size_t ws_size,
                              hipStream_t stream) {
  const float* x       = (const float*)d_in[0];
  const float* ln_w    = (const float*)d_in[1];
  const float* ln_b    = (const float*)d_in[2];
  const float* qkv_w   = (const float*)d_in[3];
  const float* qkv_b   = (const float*)d_in[4];
  const float* qk_s    = (const float*)d_in[5];
  const float* out_w   = (const float*)d_in[6];
  const float* out_b   = (const float*)d_in[7];
  const float* inv_frq = (const float*)d_in[8];

  // ws (33.55 MB): xn bf16 [8.39 MB] | qkv bf16 [25.17 MB]
  u16* ws   = (u16*)d_ws;
  u16* xn   = ws;                               // 4096*1024 (LN out, later attn out)
  u16* qkv  = ws + (size_t)4096 * 1024;         // 4096*3072 (q,k normalized in place)
  // d_out is fp32 [16.78 MB]; stage bf16 scratch inside it while it's dead:
  u16* wq_b = (u16*)d_out;                      // [0, 6.29 MB): bf16 qkv_w
  float2* cs_tab = (float2*)((char*)d_out + 6291456);  // [6.29, 6.30 MB): cos/sin table
  u16* vt   = (u16*)d_out + (size_t)4194304;    // [8.39, 16.78 MB): bf16 V^T

  k_prep<<<7172, 256, 0, stream>>>(qkv_w, wq_b, inv_frq, cs_tab, x, ln_w, ln_b, xn);
  k_gemm_b<<<dim3(24, 32), 256, 0, stream>>>(xn, wq_b, qkv_b, qkv, 4096, 3072, 1024);
  k_rotv<<<4096, 256, 0, stream>>>(qkv, cs_tab, qk_s, vt);
  k_attn<<<dim3(8, 32), 512, 0, stream>>>(qkv, vt, xn);
  k_gemm_fw<<<dim3(8, 64), 256, 0, stream>>>(xn, out_w, out_b, (float*)d_out, 4096, 1024, 1024);
}

// Round 11
// 212.894 us; speedup vs baseline: 1.2639x; 1.0160x over previous
//
#include <hip/hip_runtime.h>

typedef unsigned short u16;
typedef __attribute__((ext_vector_type(8))) short bf16x8;   // 8 bf16 in 4 VGPRs (MFMA A/B frag)
typedef __attribute__((ext_vector_type(4))) float f32x4;    // MFMA C/D frag

#define SS 2048
#define EE 1024
#define HH 16
#define DD 64

__device__ __forceinline__ float b2f(u16 u) {
  union { unsigned int i; float f; } v; v.i = ((unsigned int)u) << 16; return v.f;
}
__device__ __forceinline__ u16 f2b(float f) {
  union { float f; unsigned int i; } v; v.f = f;
  unsigned int i = v.i;
  return (u16)((i + 0x7FFFu + ((i >> 16) & 1u)) >> 16);  // RNE
}
__device__ __forceinline__ unsigned int cvt_pk_bf16(float lo, float hi) {
  unsigned int r;
  asm("v_cvt_pk_bf16_f32 %0, %1, %2" : "=v"(r) : "v"(lo), "v"(hi));  // RNE pack, low=lo
  return r;
}

// async global->LDS, 16B per lane (m97 pattern; LDS dest = wave-uniform base + lane*16)
#define GLD16(g, l)                                                         \
  __builtin_amdgcn_global_load_lds(                                         \
      (const __attribute__((address_space(1))) unsigned int*)(g),           \
      (__attribute__((address_space(3))) unsigned int*)(l), 16, 0, 0)

// ---------------- fused prep: qkv_w cvt | trig table | LayerNorm ----------------
// blocks [0,3072): cvt qkv_w -> bf16; [3072,3076): cos/sin table; [3076,7172): LN rows
__global__ __launch_bounds__(256) void k_prep(const float* __restrict__ qkv_w,
                                              u16* __restrict__ wq_b,
                                              const float* __restrict__ inv_freq,
                                              float2* __restrict__ cs,
                                              const float* __restrict__ x,
                                              const float* __restrict__ lw,
                                              const float* __restrict__ lb,
                                              u16* __restrict__ xn) {
  const int bx = blockIdx.x, t = threadIdx.x;
  if (bx < 3072) {
    const int i = bx * 256 + t;
    float4 v = ((const float4*)qkv_w)[i];
    ushort4 o;
    o.x = f2b(v.x); o.y = f2b(v.y); o.z = f2b(v.z); o.w = f2b(v.w);
    ((ushort4*)wq_b)[i] = o;
    return;
  }
  if (bx < 3076) {
    const int i = (bx - 3072) * 256 + t;
    float th = 2048.0f * inv_freq[i];
    cs[i] = make_float2(cosf(th), sinf(th));
    return;
  }
  const int row = bx - 3076;
  float4 v = ((const float4*)(x + (size_t)row * EE))[t];
  float f0 = v.x, f1 = v.y, f2 = v.z, f3 = v.w;
  float s = f0 + f1 + f2 + f3;
  float ss = f0 * f0 + f1 * f1 + f2 * f2 + f3 * f3;
  for (int o = 1; o < 64; o <<= 1) { s += __shfl_xor(s, o); ss += __shfl_xor(ss, o); }
  __shared__ float red[8];
  int w = t >> 6;
  if ((t & 63) == 0) { red[w] = s; red[4 + w] = ss; }
  __syncthreads();
  s = red[0] + red[1] + red[2] + red[3];
  ss = red[4] + red[5] + red[6] + red[7];
  float mu = s * (1.0f / 1024.0f);
  float var = ss * (1.0f / 1024.0f) - mu * mu;
  float rstd = rsqrtf(var + 1e-5f);
  float4 wv = ((const float4*)lw)[t];
  float4 bv = ((const float4*)lb)[t];
  ushort4 o;
  o.x = f2b((f0 - mu) * rstd * wv.x + bv.x);
  o.y = f2b((f1 - mu) * rstd * wv.y + bv.y);
  o.z = f2b((f2 - mu) * rstd * wv.z + bv.z);
  o.w = f2b((f3 - mu) * rstd * wv.w + bv.w);
  ((ushort4*)(xn + (size_t)row * EE))[t] = o;
}

// ---- MFMA GEMM  C[M,N] = A[M,K] * W[N,K]^T + bias (bf16 A and W) ----
// m97 structure: 128x128 tile, BK=32, linear LDS, global_load_lds x16
// (XCD swizzle reverted: L3-fit operands -> swizzle measured as a net cost)
__global__ __launch_bounds__(256) void k_gemm_b(const u16* __restrict__ A,
                                                const u16* __restrict__ W,
                                                const float* __restrict__ bias,
                                                u16* __restrict__ C,
                                                int M, int N, int K) {
  __shared__ __align__(16) u16 As[128 * 32];
  __shared__ __align__(16) u16 Ws[128 * 32];
  const int t = threadIdx.x;
  const int m0 = blockIdx.y * 128, n0 = blockIdx.x * 128;
  const int lane = t & 63, w = t >> 6, quad = lane >> 4, l15 = lane & 15;
  const int wm = (w & 1) * 64, wn = (w >> 1) * 64;

  f32x4 zero4 = {0.f, 0.f, 0.f, 0.f};
  f32x4 acc[4][4];
  for (int mi = 0; mi < 4; mi++)
    for (int ni = 0; ni < 4; ni++) acc[mi][ni] = zero4;

  const u16* Ag = A + (size_t)(m0 + (t >> 2)) * K + (t & 3) * 8;
  const u16* Wg = W + (size_t)(n0 + (t >> 2)) * K + (t & 3) * 8;
  const size_t rowskip = (size_t)64 * K;

  for (int k0 = 0; k0 < K; k0 += 32) {
    GLD16(Ag + k0, As + t * 8);
    GLD16(Ag + rowskip + k0, As + 2048 + t * 8);
    GLD16(Wg + k0, Ws + t * 8);
    GLD16(Wg + rowskip + k0, Ws + 2048 + t * 8);
    __syncthreads();
    bf16x8 af[4], wf[4];
#pragma unroll
    for (int i = 0; i < 4; i++) {
      af[i] = *(const bf16x8*)(As + (wm + i * 16 + l15) * 32 + quad * 8);
      wf[i] = *(const bf16x8*)(Ws + (wn + i * 16 + l15) * 32 + quad * 8);
    }
#pragma unroll
    for (int mi = 0; mi < 4; mi++)
#pragma unroll
      for (int ni = 0; ni < 4; ni++)
        acc[mi][ni] = __builtin_amdgcn_mfma_f32_16x16x32_bf16(af[mi], wf[ni], acc[mi][ni], 0, 0, 0);
    __syncthreads();
  }
  for (int mi = 0; mi < 4; mi++)
    for (int ni = 0; ni < 4; ni++) {
      int col = n0 + wn + ni * 16 + l15;
      float bb = bias[col];
      for (int r = 0; r < 4; r++) {
        int grow = m0 + wm + mi * 16 + quad * 4 + r;
        C[(size_t)grow * N + col] = f2b(acc[mi][ni][r] + bb);
      }
    }
}

// ---- MFMA GEMM with fp32 W (converted in-flight; replaces k_cvt + bf16 gemm_f) ----
// 64x128 tile: As via GLD16; W fp32 reg-staged -> cvt_pk -> linear b128 ds_write
__global__ __launch_bounds__(256) void k_gemm_fw(const u16* __restrict__ A,
                                                 const float* __restrict__ W,
                                                 const float* __restrict__ bias,
                                                 float* __restrict__ C,
                                                 int M, int N, int K) {
  __shared__ __align__(16) u16 As[64 * 32];
  __shared__ __align__(16) u16 Ws[128 * 32];
  const int t = threadIdx.x;
  const int m0 = blockIdx.y * 64, n0 = blockIdx.x * 128;
  const int lane = t & 63, w = t >> 6, quad = lane >> 4, l15 = lane & 15;
  const int wm = (w & 1) * 32, wn = (w >> 1) * 64;

  f32x4 zero4 = {0.f, 0.f, 0.f, 0.f};
  f32x4 acc[2][4];
  for (int mi = 0; mi < 2; mi++)
    for (int ni = 0; ni < 4; ni++) acc[mi][ni] = zero4;

  const u16* Ag = A + (size_t)(m0 + (t >> 2)) * K + (t & 3) * 8;
  const float* Wg0 = W + (size_t)(n0 + (t >> 2)) * K + (t & 3) * 8;
  const float* Wg1 = Wg0 + (size_t)64 * K;

  for (int k0 = 0; k0 < K; k0 += 32) {
    GLD16(Ag + k0, As + t * 8);
    float4 wa = *(const float4*)(Wg0 + k0);
    float4 wb = *(const float4*)(Wg0 + k0 + 4);
    float4 wc = *(const float4*)(Wg1 + k0);
    float4 wd = *(const float4*)(Wg1 + k0 + 4);
    union { unsigned int u[4]; bf16x8 v8; } p0, p1;
    p0.u[0] = cvt_pk_bf16(wa.x, wa.y); p0.u[1] = cvt_pk_bf16(wa.z, wa.w);
    p0.u[2] = cvt_pk_bf16(wb.x, wb.y); p0.u[3] = cvt_pk_bf16(wb.z, wb.w);
    p1.u[0] = cvt_pk_bf16(wc.x, wc.y); p1.u[1] = cvt_pk_bf16(wc.z, wc.w);
    p1.u[2] = cvt_pk_bf16(wd.x, wd.y); p1.u[3] = cvt_pk_bf16(wd.z, wd.w);
    *(bf16x8*)(Ws + t * 8) = p0.v8;         // rows 0..63, linear (conflict-free)
    *(bf16x8*)(Ws + 2048 + t * 8) = p1.v8;  // rows 64..127
    __syncthreads();
    bf16x8 af[2], wf[4];
#pragma unroll
    for (int i = 0; i < 2; i++)
      af[i] = *(const bf16x8*)(As + (wm + i * 16 + l15) * 32 + quad * 8);
#pragma unroll
    for (int i = 0; i < 4; i++)
      wf[i] = *(const bf16x8*)(Ws + (wn + i * 16 + l15) * 32 + quad * 8);
#pragma unroll
    for (int mi = 0; mi < 2; mi++)
#pragma unroll
      for (int ni = 0; ni < 4; ni++)
        acc[mi][ni] = __builtin_amdgcn_mfma_f32_16x16x32_bf16(af[mi], wf[ni], acc[mi][ni], 0, 0, 0);
    __syncthreads();
  }
  for (int mi = 0; mi < 2; mi++)
    for (int ni = 0; ni < 4; ni++) {
      int col = n0 + wn + ni * 16 + l15;
      float bb = bias[col];
      for (int r = 0; r < 4; r++) {
        int grow = m0 + wm + mi * 16 + quad * 4 + r;
        C[(size_t)grow * N + col] = acc[mi][ni][r] + bb;
      }
    }
}

// ------ fused: rotate+l2norm+scale (all 4096 rows) | V transpose (blocks < 1024) ------
__global__ __launch_bounds__(256) void k_rotv(u16* __restrict__ qkv,
                                              const float2* __restrict__ cs_tab,
                                              const float* __restrict__ scale_p,
                                              u16* __restrict__ vt) {
  __shared__ float qf[1024];
  __shared__ float kf[1024];
  __shared__ __align__(16) u16 tile[64 * 72];
  const int row = blockIdx.x, t = threadIdx.x;
  {
    u16* qr = qkv + (size_t)row * 3072;
    u16* kr = qr + 1024;
    ushort4 qv = ((const ushort4*)qr)[t];
    ushort4 kv = ((const ushort4*)kr)[t];
    *(float4*)(qf + 4 * t) = make_float4(b2f(qv.x), b2f(qv.y), b2f(qv.z), b2f(qv.w));
    *(float4*)(kf + 4 * t) = make_float4(b2f(kv.x), b2f(kv.y), b2f(kv.z), b2f(kv.w));
    __syncthreads();
    const float scale = scale_p[0];
    float rq[4], rk[4];
#pragma unroll
    for (int u = 0; u < 4; u++) {
      int j = 4 * t + u;
      float2 cs = cs_tab[j];
      float qrot = (j < 512) ? -qf[2 * j + 1] : qf[2 * (j - 512)];
      float krot = (j < 512) ? -kf[2 * j + 1] : kf[2 * (j - 512)];
      rq[u] = qf[j] * cs.x + qrot * cs.y;
      rk[u] = kf[j] * cs.x + krot * cs.y;
    }
    float ssq = rq[0] * rq[0] + rq[1] * rq[1] + rq[2] * rq[2] + rq[3] * rq[3];
    float ssk = rk[0] * rk[0] + rk[1] * rk[1] + rk[2] * rk[2] + rk[3] * rk[3];
    for (int o = 1; o < 16; o <<= 1) { ssq += __shfl_xor(ssq, o); ssk += __shfl_xor(ssk, o); }
    float qs = scale / fmaxf(sqrtf(ssq), 1e-12f);
    float ks = scale / fmaxf(sqrtf(ssk), 1e-12f);
    ushort4 qo, ko;
    qo.x = f2b(rq[0] * qs); qo.y = f2b(rq[1] * qs); qo.z = f2b(rq[2] * qs); qo.w = f2b(rq[3] * qs);
    ko.x = f2b(rk[0] * ks); ko.y = f2b(rk[1] * ks); ko.z = f2b(rk[2] * ks); ko.w = f2b(rk[3] * ks);
    ((ushort4*)qr)[t] = qo;
    ((ushort4*)kr)[t] = ko;
  }
  if (row >= 1024) return;
  // ---- V transpose job (reads V section: untouched by the rotnorm phase) ----
  const int st = row & 31, bh = row >> 5;
  const int b = bh >> 4, h = bh & 15;
  const int s0 = st * 64;
  const int si = t >> 2, dc = t & 3;
  __syncthreads();  // LDS reuse safety (qf/kf reads done before tile writes)
  const u16* src = qkv + (size_t)(b * SS + s0 + si) * 3072 + 2048 + h * DD;
  bf16x8 v0 = *(const bf16x8*)(src + dc * 8);
  bf16x8 v1 = *(const bf16x8*)(src + (dc + 4) * 8);
#pragma unroll
  for (int u = 0; u < 8; u++) tile[(dc * 8 + u) * 72 + si] = (u16)v0[u];
#pragma unroll
  for (int u = 0; u < 8; u++) tile[((dc + 4) * 8 + u) * 72 + si] = (u16)v1[u];
  __syncthreads();
#pragma unroll
  for (int it = 0; it < 2; it++) {
    int idx = t + it * 256;
    int d = idx >> 3, ch = idx & 7;
    bf16x8 o = *(const bf16x8*)(tile + d * 72 + ch * 8);
    *(bf16x8*)(vt + (size_t)(bh * DD + d) * SS + s0 + ch * 8) = o;
  }
}

// ---------------- causal flash attention (MFMA, swapped QK^T, in-register P) ----------------
// QBLK=128 via 8 warps; KBLK=128. Grid (32,16): bh = blockIdx.x, qt = y<8 ? y : 23-y
// (co-resident block pairs f,f+256 have qt summing to 15 -> balanced CU load).
// 2 blocks/CU (LDS 71.7 KB) -> 4 waves/SIMD.
// SWAPPED QK^T: lane (quad,l15) holds P[k=16n+4quad+r][q=16w+l15]; lane-local
// softmax + 2 shfl_xor. IN-REGISTER P: PV A-frag built by cross-quad shfl —
// word sources live at lanes (quad&1)*32+l15 and +16, register n = 2c+(quad>>1)
// (derivation: 16n+4quad'+r = 32c+8quad+j). No Pt LDS, no lgkm drain.
__global__ __launch_bounds__(512, 4) void k_attn(const u16* __restrict__ qkv,
                                                 const u16* __restrict__ vt,
                                                 u16* __restrict__ out) {
  __shared__ __align__(16) u16 Kt[2][128 * 72];    // K rows (d=0..63 + pad)
  __shared__ __align__(16) u16 Vt[2][64 * 136];    // V^T rows d, k=0..127 + pad
  const int bh = blockIdx.x;
  const int y = blockIdx.y;
  const int qt = (y < 8) ? y : 23 - y;             // 128-row q-tile, 0..15
  const int b = bh >> 4, h = bh & 15;
  const int t = threadIdx.x, w = t >> 6, lane = t & 63, quad = lane >> 4, l15 = lane & 15;
  const int krow = t >> 2, kq = (t & 3) * 16;  // K staging: row 0..127, 16-u16 quarter
  const int dr = t >> 3, kc8 = t & 7;          // V staging: d-row 0..63, 16-k eighth
  const int srcl = (lane & 48) + ((lane >> 4) << 2);  // 20*quad: state-holder base lane
  const int qA = ((lane >> 4) & 1) * 32 + l15;        // P-exchange src lane (quad'=(quad&1)*2)
  const int qB = qA + 16;
  const bool hiN = (quad >> 1) & 1;                   // use n=2c+1 register set
  const u16* kn = qkv + 1024;
  f32x4 zero4 = {0.f, 0.f, 0.f, 0.f};
  const int q0 = qt * 128;

  bf16x8 qf[2];
  {
    const u16* qrow = qkv + (size_t)(b * SS + q0 + 16 * w + l15) * 3072 + h * DD;
    qf[0] = *(const bf16x8*)(qrow + quad * 8);
    qf[1] = *(const bf16x8*)(qrow + 32 + quad * 8);
  }
  f32x4 oacc[4];
  for (int n = 0; n < 4; n++) oacc[n] = zero4;
  float m_i = -1e30f, l_i = 0.f;   // per-lane: state for q-row 16w+l15

  bf16x8 kv[2], vv[2];
  // prologue: load & stage tile kt=0 into buf 0
  {
    const u16* krg = kn + (size_t)(b * SS + krow) * 3072 + h * DD + kq;
    kv[0] = *(const bf16x8*)(krg);
    kv[1] = *(const bf16x8*)(krg + 8);
    const u16* vrg = vt + (size_t)(bh * DD + dr) * SS + kc8 * 16;
    vv[0] = *(const bf16x8*)(vrg);
    vv[1] = *(const bf16x8*)(vrg + 8);
  }
  *(bf16x8*)(Kt[0] + krow * 72 + kq) = kv[0];
  *(bf16x8*)(Kt[0] + krow * 72 + kq + 8) = kv[1];
  *(bf16x8*)(Vt[0] + dr * 136 + kc8 * 16) = vv[0];
  *(bf16x8*)(Vt[0] + dr * 136 + kc8 * 16 + 8) = vv[1];
  __syncthreads();
  int cur = 0;

  for (int kt = 0; kt <= qt; kt++) {
    if (kt < qt) {  // prefetch next tile into regs; staged into buf^1 below
      const int k0n = (kt + 1) * 128;
      const u16* krg = kn + (size_t)(b * SS + k0n + krow) * 3072 + h * DD + kq;
      kv[0] = *(const bf16x8*)(krg);
      kv[1] = *(const bf16x8*)(krg + 8);
      const u16* vrg = vt + (size_t)(bh * DD + dr) * SS + k0n + kc8 * 16;
      vv[0] = *(const bf16x8*)(vrg);
      vv[1] = *(const bf16x8*)(vrg + 8);
    }
    const u16* Kc = Kt[cur];
    const u16* Vc = Vt[cur];
    // ---- swapped QK^T: A = K-group (16 k-rows), B = Q ----
    f32x4 sacc[8];
#pragma unroll
    for (int n = 0; n < 8; n++) {
      sacc[n] = zero4;
#pragma unroll
      for (int c = 0; c < 2; c++) {
        bf16x8 kfrag = *(const bf16x8*)(Kc + (n * 16 + l15) * 72 + c * 32 + quad * 8);
        sacc[n] = __builtin_amdgcn_mfma_f32_16x16x32_bf16(kfrag, qf[c], sacc[n], 0, 0, 0);
      }
    }
    if (kt == qt) {  // diagonal: mask k > q-row-in-tile; k = 16n+4quad+r, q = 16w+l15
      const int qrow = 16 * w + l15, kbase = 4 * quad;
#pragma unroll
      for (int n = 0; n < 8; n++)
#pragma unroll
        for (int r = 0; r < 4; r++)
          if (16 * n + kbase + r > qrow) sacc[n][r] = -1e30f;
    }
    // ---- lane-local softmax for q-row 16w+l15 ----
    float mx = -1e30f;
#pragma unroll
    for (int n = 0; n < 8; n++)
#pragma unroll
      for (int r = 0; r < 4; r++) mx = fmaxf(mx, sacc[n][r]);
    mx = fmaxf(mx, __shfl_xor(mx, 16));
    mx = fmaxf(mx, __shfl_xor(mx, 32));
    float mn = fmaxf(m_i, mx);
    float al = __expf(m_i - mn);
    m_i = mn;
    float rs = 0.f;
#pragma unroll
    for (int n = 0; n < 8; n++)
#pragma unroll
      for (int r = 0; r < 4; r++) {
        float p = __expf(sacc[n][r] - mn);
        sacc[n][r] = p;
        rs += p;
      }
    rs += __shfl_xor(rs, 16);
    rs += __shfl_xor(rs, 32);
    l_i = al * l_i + rs;
    // broadcast al to O-row holders (O row q = quad*4+r; state at lane 20*quad+r)
    float alr[4];
#pragma unroll
    for (int r = 0; r < 4; r++) alr[r] = __shfl(al, srcl + r);
#pragma unroll
    for (int n = 0; n < 4; n++)
#pragma unroll
      for (int r = 0; r < 4; r++) oacc[n][r] *= alr[r];
    // ---- P pack to bf16 pairs, kept in registers ----
    unsigned int pkw[8][2];
#pragma unroll
    for (int n = 0; n < 8; n++) {
      pkw[n][0] = cvt_pk_bf16(sacc[n][0], sacc[n][1]);
      pkw[n][1] = cvt_pk_bf16(sacc[n][2], sacc[n][3]);
    }
    // ---- PV: A-frag built via cross-quad shfl (no LDS P) ----
#pragma unroll
    for (int c = 0; c < 4; c++) {
      unsigned int a0 = __shfl(pkw[2 * c][0], qA);
      unsigned int a1 = __shfl(pkw[2 * c][1], qA);
      unsigned int a2 = __shfl(pkw[2 * c][0], qB);
      unsigned int a3 = __shfl(pkw[2 * c][1], qB);
      unsigned int b0 = __shfl(pkw[2 * c + 1][0], qA);
      unsigned int b1 = __shfl(pkw[2 * c + 1][1], qA);
      unsigned int b2 = __shfl(pkw[2 * c + 1][0], qB);
      unsigned int b3 = __shfl(pkw[2 * c + 1][1], qB);
      union { unsigned int u[4]; bf16x8 v8; } pf;
      pf.u[0] = hiN ? b0 : a0;
      pf.u[1] = hiN ? b1 : a1;
      pf.u[2] = hiN ? b2 : a2;
      pf.u[3] = hiN ? b3 : a3;
#pragma unroll
      for (int n = 0; n < 4; n++) {
        bf16x8 vf = *(const bf16x8*)(Vc + (n * 16 + l15) * 136 + c * 32 + quad * 8);
        oacc[n] = __builtin_amdgcn_mfma_f32_16x16x32_bf16(pf.v8, vf, oacc[n], 0, 0, 0);
      }
    }
    if (kt < qt) {  // stage prefetched tile into the other buffer (no race: buf^1)
      *(bf16x8*)(Kt[cur ^ 1] + krow * 72 + kq) = kv[0];
      *(bf16x8*)(Kt[cur ^ 1] + krow * 72 + kq + 8) = kv[1];
      *(bf16x8*)(Vt[cur ^ 1] + dr * 136 + kc8 * 16) = vv[0];
      *(bf16x8*)(Vt[cur ^ 1] + dr * 136 + kc8 * 16 + 8) = vv[1];
    }
    __syncthreads();  // single barrier: buf[cur] readers done + buf^1 staged
    cur ^= 1;
  }
  float lr[4];
#pragma unroll
  for (int r = 0; r < 4; r++) lr[r] = __shfl(l_i, srcl + r);
  for (int n = 0; n < 4; n++)
    for (int r = 0; r < 4; r++) {
      int row = q0 + 16 * w + quad * 4 + r;
      out[(size_t)(b * SS + row) * EE + h * DD + n * 16 + l15] = f2b(oacc[n][r] / lr[r]);
    }
}

extern "C" void kernel_launch(void* const* d_in, const int* in_sizes, int n_in,
                              void* d_out, int out_size, void* d_ws, size_t ws_size,
                              hipStream_t stream) {
  const float* x       = (const float*)d_in[0];
  const float* ln_w    = (const float*)d_in[1];
  const float* ln_b    = (const float*)d_in[2];
  const float* qkv_w   = (const float*)d_in[3];
  const float* qkv_b   = (const float*)d_in[4];
  const float* qk_s    = (const float*)d_in[5];
  const float* out_w   = (const float*)d_in[6];
  const float* out_b   = (const float*)d_in[7];
  const float* inv_frq = (const float*)d_in[8];

  // ws (33.55 MB): xn bf16 [8.39 MB] | qkv bf16 [25.17 MB]
  u16* ws   = (u16*)d_ws;
  u16* xn   = ws;                               // 4096*1024 (LN out, later attn out)
  u16* qkv  = ws + (size_t)4096 * 1024;         // 4096*3072 (q,k normalized in place)
  // d_out is fp32 [16.78 MB]; stage bf16 scratch inside it while it's dead:
  u16* wq_b = (u16*)d_out;                      // [0, 6.29 MB): bf16 qkv_w
  float2* cs_tab = (float2*)((char*)d_out + 6291456);  // [6.29, 6.30 MB): cos/sin table
  u16* vt   = (u16*)d_out + (size_t)4194304;    // [8.39, 16.78 MB): bf16 V^T

  k_prep<<<7172, 256, 0, stream>>>(qkv_w, wq_b, inv_frq, cs_tab, x, ln_w, ln_b, xn);
  k_gemm_b<<<dim3(24, 32), 256, 0, stream>>>(xn, wq_b, qkv_b, qkv, 4096, 3072, 1024);
  k_rotv<<<4096, 256, 0, stream>>>(qkv, cs_tab, qk_s, vt);
  k_attn<<<dim3(32, 16), 512, 0, stream>>>(qkv, vt, xn);
  k_gemm_fw<<<dim3(8, 64), 256, 0, stream>>>(xn, out_w, out_b, (float*)d_out, 4096, 1024, 1024);
}